// Round 13
// baseline (406.406 us; speedup 1.0000x reference)
//
#include <hip/hip_runtime.h>
#include <hip/hip_bf16.h>
#include <limits.h>

// ---------------- problem constants ----------------
#define N_NODES 50000
#define N_EDGES 800000
#define TOT_E   (N_EDGES + N_NODES)   // with self loops
#define IN_F    38
#define HIDC    64
#define NH      4
#define F1      256                    // NH*HIDC
#define F2      128                    // OUT
#define NGRAPH  128
#define NEG_SLOPE 0.2f
#define EPS_A   1e-16f

typedef __hip_bfloat16 bf16;
typedef __attribute__((ext_vector_type(8))) short short8;
typedef __attribute__((ext_vector_type(16))) float f32x16;
typedef __attribute__((ext_vector_type(2))) float f2;   // lowers to VOP3P v_pk_*_f32

// ---------------- ws layout ----------------
constexpr size_t al256(size_t x) { return (x + 255) & ~(size_t)255; }

// converted-params element offsets (f32 elements) — contiguous in this order
#define P_WL1   0
#define P_BL1   (P_WL1 + IN_F * F1)        // 9728
#define P_WR1   (P_BL1 + F1)               // 9984
#define P_BR1   (P_WR1 + IN_F * F1)        // 19712
#define P_ATT1  (P_BR1 + F1)               // 19968
#define P_BIAS1 (P_ATT1 + F1)              // 20224
#define P_WL2   (P_BIAS1 + F1)             // 20480
#define P_BL2   (P_WL2 + F1 * F2)          // 53248
#define P_WR2   (P_BL2 + F2)               // 53376
#define P_BR2   (P_WR2 + F1 * F2)          // 86144
#define P_ATT2  (P_BR2 + F2)               // 86272
#define P_BIAS2 (P_ATT2 + F2)              // 86400
#define P_TOTAL (P_BIAS2 + F2)             // 86528 = 338*256 exactly

constexpr size_t OFF_PAR  = 256;
constexpr size_t OFF_XL1  = OFF_PAR + al256((size_t)P_TOTAL * 4);   // reused as h2 later
constexpr size_t OFF_XR1  = OFF_XL1 + al256((size_t)N_NODES * F1 * 2);
constexpr size_t OFF_H    = OFF_XR1 + al256((size_t)N_NODES * F1 * 2);
constexpr size_t OFF_XL2  = OFF_H   + al256((size_t)N_NODES * F1 * 2);
constexpr size_t OFF_XR2  = OFF_XL2 + al256((size_t)N_NODES * F2 * 2);
constexpr size_t OFF_CNT  = OFF_XR2 + al256((size_t)N_NODES * F2 * 2);
constexpr size_t OFF_OFFS = OFF_CNT + al256((size_t)N_NODES * 4);
constexpr size_t OFF_CSR  = OFF_OFFS+ al256((size_t)(N_NODES + 1) * 4);
constexpr size_t OFF_GS   = OFF_CSR + al256((size_t)TOT_E * 4);
constexpr size_t OFF_GE   = OFF_GS  + al256((size_t)NGRAPH * 4);    // adjacent to GS
constexpr size_t OFF_WT1  = OFF_GE  + al256((size_t)NGRAPH * 4);    // 512x64 bf16
constexpr size_t OFF_WT2  = OFF_WT1 + al256((size_t)512 * 64 * 2);  // 256x256 bf16
constexpr size_t OFF_BS   = OFF_WT2 + al256((size_t)256 * 256 * 2); // 49 block sums
constexpr size_t OFF_RANK = OFF_BS  + al256(64 * 4);                // per-edge rank
constexpr size_t OFF_H2   = OFF_XL1;  // xl1 dead after agg1
constexpr size_t OFF_XB   = OFF_H;    // xb (N x 64 bf16) dead before agg1 writes h

#define SCAN_BLKS 49   // ceil(50000/1024)
#define GBLK 1563      // ceil(50000/32)  gemm row-blocks
#define SBL  831       // ceil(TOT_E/1024) scatter blocks (4 edges/thread)

// ---------------- helpers ----------------
// uint4 (8 bf16) -> 4 x f2; pairs are (ch 2i, ch 2i+1)
__device__ __forceinline__ void unpack8bf2(uint4 q, f2* f) {
  unsigned v[4] = {q.x, q.y, q.z, q.w};
#pragma unroll
  for (int i = 0; i < 4; i++) {
    f2 t;
    t.x = __uint_as_float(v[i] << 16);
    t.y = __uint_as_float(v[i] & 0xffff0000u);
    f[i] = t;
  }
}

__device__ __forceinline__ void load8bf2(const bf16* __restrict__ p, f2* f) {
  unpack8bf2(*(const uint4*)p, f);
}

// leaky_relu(s) = 0.6*s + 0.4*|s|
__device__ __forceinline__ f2 lrelu2(f2 s) {
  f2 as;
  as.x = __uint_as_float(__float_as_uint(s.x) & 0x7fffffffu);
  as.y = __uint_as_float(__float_as_uint(s.y) & 0x7fffffffu);
  return 0.6f * s + 0.4f * as;
}

// wave-cooperative dtype sniff: 1 = inputs are f32, 0 = bf16.
__device__ __forceinline__ int detect_f32_wave(const void* __restrict__ x) {
  const unsigned short* u = (const unsigned short*)x;
  unsigned short b = u[threadIdx.x & 63];
  int e = (b >> 7) & 0xFF;
  unsigned long long m = __ballot(!((e == 0) || (e >= 96 && e <= 158)));
  return __popcll(m) > 8;
}

// ---------------- fused prep kernel ----------------
#define B_CVT  338
#define B_XP   12500
#define B_W1   128
#define B_W2   256
#define B_BND  196
#define B_CNT  3321

struct PrepArgs {
  const void* x;
  const void* src[12];     // Wl1,bl1,Wr1,br1,att1,bias1,Wl2,bl2,Wr2,br2,att2,bias2
  const int* ei;
  const int* batch;
};

__global__ __launch_bounds__(256) void prep_k(
    PrepArgs a, float* __restrict__ par, bf16* __restrict__ xb,
    bf16* __restrict__ wt1, bf16* __restrict__ wt2,
    int* __restrict__ gs, int* __restrict__ ge, int* __restrict__ cnt,
    int* __restrict__ rank) {
  int b = blockIdx.x;
  const int tid = threadIdx.x;

  if (b < B_CVT) {                       // ---- param convert -> f32 ----
    const int flag = detect_f32_wave(a.x);
    int idx = b * 256 + tid;             // [0, P_TOTAL)
    const void* p; int base;
    if      (idx < P_BL1)  { p = a.src[0];  base = P_WL1; }
    else if (idx < P_WR1)  { p = a.src[1];  base = P_BL1; }
    else if (idx < P_BR1)  { p = a.src[2];  base = P_WR1; }
    else if (idx < P_ATT1) { p = a.src[3];  base = P_BR1; }
    else if (idx < P_BIAS1){ p = a.src[4];  base = P_ATT1; }
    else if (idx < P_WL2)  { p = a.src[5];  base = P_BIAS1; }
    else if (idx < P_BL2)  { p = a.src[6];  base = P_WL2; }
    else if (idx < P_WR2)  { p = a.src[7];  base = P_BL2; }
    else if (idx < P_BR2)  { p = a.src[8];  base = P_WR2; }
    else if (idx < P_ATT2) { p = a.src[9];  base = P_BR2; }
    else if (idx < P_BIAS2){ p = a.src[10]; base = P_ATT2; }
    else                   { p = a.src[11]; base = P_BIAS2; }
    int li = idx - base;
    par[idx] = flag ? ((const float*)p)[li] : (float)((const bf16*)p)[li];
    return;
  }
  b -= B_CVT;
  if (b < B_XP) {                        // ---- x -> xb (N x 64, zero-pad K) ----
    const int flag = detect_f32_wave(a.x);
    int i = b * 256 + tid;               // n*64 + k
    int n = i >> 6, k = i & 63;
    float v = 0.f;
    if (k < IN_F) {
      int idx = n * IN_F + k;
      v = flag ? ((const float*)a.x)[idx] : (float)((const bf16*)a.x)[idx];
    }
    xb[i] = (bf16)v;
    return;
  }
  b -= B_XP;
  if (b < B_W1) {                        // ---- Wt1[n][k] 512x64 ----
    const int flag = detect_f32_wave(a.x);
    int i = b * 256 + tid;
    int n = i >> 6, k = i & 63;
    float v = 0.f;
    if (k < IN_F) {
      const void* W = (n < F1) ? a.src[0] : a.src[2];
      int col = (n < F1) ? n : n - F1;
      int idx = k * F1 + col;
      v = flag ? ((const float*)W)[idx] : (float)((const bf16*)W)[idx];
    }
    wt1[i] = (bf16)v;
    return;
  }
  b -= B_W1;
  if (b < B_W2) {                        // ---- Wt2[n][k] 256x256 ----
    const int flag = detect_f32_wave(a.x);
    int i = b * 256 + tid;
    int n = i >> 8, k = i & 255;
    const void* W = (n < F2) ? a.src[6] : a.src[8];
    int col = (n < F2) ? n : n - F2;
    int idx = k * F2 + col;
    float v = flag ? ((const float*)W)[idx] : (float)((const bf16*)W)[idx];
    wt2[i] = (bf16)v;
    return;
  }
  b -= B_W2;
  if (b < B_BND) {                       // ---- graph bounds (batch sorted) ----
    int n = b * 256 + tid;
    if (n >= N_NODES) return;
    int bb = a.batch[n];
    if (n == 0) gs[bb] = 0;
    else {
      int bp = a.batch[n - 1];
      if (bp != bb) { gs[bb] = n; ge[bp] = n - 1; }
    }
    if (n == N_NODES - 1) ge[bb] = N_NODES - 1;
    return;
  }
  b -= B_BND;
  {                                      // ---- degree count + per-edge rank ----
    int e = b * 256 + tid;
    if (e >= TOT_E) return;
    int dst = (e < N_EDGES) ? a.ei[N_EDGES + e] : (e - N_EDGES);
    rank[e] = atomicAdd(&cnt[dst], 1);   // rank within dst (order-free)
  }
}

// ---------------- fused: GEMM1 (MFMA 32x32x16) || atomic-free scatter ----------------
__global__ __launch_bounds__(256) void gemm1_scatter_k(
    const bf16* __restrict__ xb, const bf16* __restrict__ wt1,
    const float* __restrict__ par,
    bf16* __restrict__ xl1, bf16* __restrict__ xr1,
    const int* __restrict__ ei, const int* __restrict__ offs,
    const int* __restrict__ rank, int* __restrict__ csr) {
  if (blockIdx.x >= GBLK) {              // ---- scatter path ----
    int base = (blockIdx.x - GBLK) * 1024 + threadIdx.x;
#pragma unroll
    for (int i = 0; i < 4; i++) {
      int e = base + i * 256;
      if (e >= TOT_E) continue;
      int src, dst;
      if (e < N_EDGES) { src = ei[e]; dst = ei[N_EDGES + e]; }
      else             { src = dst = e - N_EDGES; }
      csr[offs[dst] + rank[e]] = src;
    }
    return;
  }
  // ---- gemm1 path: 32x32x16 MFMA. Wave w: rows blk*32..+31, cols w*128..+127 ----
  const int w = threadIdx.x >> 6, lane = threadIdx.x & 63;
  const int m0 = blockIdx.x * 32;
  const int colbase = w * 128;
  const int lm = lane & 31;       // m / n index
  const int kh = lane >> 5;       // k-half (8 of 16)

  int arow = m0 + lm; if (arow >= N_NODES) arow = N_NODES - 1;
  short8 afr[4];
#pragma unroll
  for (int kk = 0; kk < 4; kk++)
    afr[kk] = *(const short8*)(xb + (size_t)arow * 64 + kk * 16 + kh * 8);

  f32x16 acc[4] = {};
#pragma unroll
  for (int t = 0; t < 4; t++) {
    int n = colbase + t * 32 + lm;
#pragma unroll
    for (int kk = 0; kk < 4; kk++) {
      short8 b = *(const short8*)(wt1 + (size_t)n * 64 + kk * 16 + kh * 8);
      acc[t] = __builtin_amdgcn_mfma_f32_32x32x16_bf16(afr[kk], b, acc[t], 0, 0, 0);
    }
  }

  // C/D: col = lane&31 (+tile), row = (reg&3) + 8*(reg>>2) + 4*kh  [m74/m101]
#pragma unroll
  for (int t = 0; t < 4; t++) {
    int col = colbase + t * 32 + lm;
    bf16* dst = (col < F1) ? xl1 : xr1;
    int c = (col < F1) ? col : col - F1;
    float bv = (col < F1) ? par[P_BL1 + c] : par[P_BR1 + c];
#pragma unroll
    for (int reg = 0; reg < 16; reg++) {
      int row = m0 + (reg & 3) + 8 * (reg >> 2) + 4 * kh;
      if (row < N_NODES)
        dst[(size_t)row * F1 + c] = (bf16)(acc[t][reg] + bv);
    }
  }
}

// ---------------- GEMM 2 (MFMA 32x32x16): h(N,256) @ Wt2^T -> xl2|xr2 ----------------
__global__ __launch_bounds__(256) void gemm2_mfma_k(
    const bf16* __restrict__ h, const bf16* __restrict__ wt2,
    const float* __restrict__ par,
    bf16* __restrict__ xl2, bf16* __restrict__ xr2) {
  const int w = threadIdx.x >> 6, lane = threadIdx.x & 63;
  const int m0 = blockIdx.x * 32;
  const int colbase = w * 64;
  const int lm = lane & 31;
  const int kh = lane >> 5;

  int arow = m0 + lm; if (arow >= N_NODES) arow = N_NODES - 1;
  const bf16* hrow = h + (size_t)arow * F1 + kh * 8;

  f32x16 acc[2] = {};
#pragma unroll
  for (int kk = 0; kk < 16; kk++) {
    short8 a = *(const short8*)(hrow + kk * 16);
#pragma unroll
    for (int t = 0; t < 2; t++) {
      int n = colbase + t * 32 + lm;
      short8 b = *(const short8*)(wt2 + (size_t)n * 256 + kk * 16 + kh * 8);
      acc[t] = __builtin_amdgcn_mfma_f32_32x32x16_bf16(a, b, acc[t], 0, 0, 0);
    }
  }

#pragma unroll
  for (int t = 0; t < 2; t++) {
    int col = colbase + t * 32 + lm;
    bf16* dst = (col < F2) ? xl2 : xr2;
    int c = (col < F2) ? col : col - F2;
    float bv = (col < F2) ? par[P_BL2 + c] : par[P_BR2 + c];
#pragma unroll
    for (int reg = 0; reg < 16; reg++) {
      int row = m0 + (reg & 3) + 8 * (reg >> 2) + 4 * kh;
      if (row < N_NODES)
        dst[(size_t)row * F2 + c] = (bf16)(acc[t][reg] + bv);
    }
  }
}

// ---------------- CSR scan (2-phase) ----------------
__global__ __launch_bounds__(1024) void scan_a(const int* __restrict__ cnt,
                                               int* __restrict__ offs,
                                               int* __restrict__ bsum) {
  __shared__ int wsum[16];
  const int t = threadIdx.x;
  const int lane = t & 63, w = t >> 6;
  int idx = blockIdx.x * 1024 + t;
  int v = (idx < N_NODES) ? cnt[idx] : 0;
  int s = v;
#pragma unroll
  for (int off = 1; off < 64; off <<= 1) {
    int u = __shfl_up(s, off, 64);
    if (lane >= off) s += u;
  }
  if (lane == 63) wsum[w] = s;
  __syncthreads();
  int prefix = 0;
  for (int i = 0; i < w; i++) prefix += wsum[i];
  if (idx < N_NODES) offs[idx] = prefix + s - v;   // exclusive within block
  if (t == 1023) bsum[blockIdx.x] = prefix + s;    // block total
}

// Each block recomputes the 49-element block-sum prefix (cheap) — no scan_b.
__global__ void scan_c(const int* __restrict__ bsum, int* __restrict__ offs) {
  const int t = threadIdx.x;
  const int grp = blockIdx.x >> 2;     // 1024-group of this block (constant)
  __shared__ int sboff;
  if (t < 64) {
    int v = (t < SCAN_BLKS) ? bsum[t] : 0;
    int s = v;
#pragma unroll
    for (int off = 1; off < 64; off <<= 1) {
      int u = __shfl_up(s, off, 64);
      if (t >= off) s += u;
    }
    if (t == grp) sboff = s - v;       // exclusive prefix at grp
  }
  __syncthreads();
  int idx = blockIdx.x * 256 + t;
  if (idx < N_NODES) offs[idx] += sboff;
  if (blockIdx.x == 0 && t == 0) offs[N_NODES] = TOT_E;  // grand total is constant
}

// ---------------- layer-1 aggregation: one wave per dst, 2 groups x 32 lanes,
// 2-deep register prefetch pipeline ----------------
__global__ __launch_bounds__(256, 8) void agg1_k(
    const bf16* __restrict__ xl1, const bf16* __restrict__ xr1,
    const float* __restrict__ par,
    const int* __restrict__ offs, const int* __restrict__ csr,
    bf16* __restrict__ hout) {
  const int dst = blockIdx.x * 4 + (threadIdx.x >> 6);
  if (dst >= N_NODES) return;
  const int lane = threadIdx.x & 63;
  const int g = lane >> 5;        // 2 edge groups
  const int sl = lane & 31;
  const int chb = sl * 8;

  f2 r2[4], a2[4];
  load8bf2(xr1 + (size_t)dst * F1 + chb, r2);
  {
    float4 aa = *(const float4*)(par + P_ATT1 + chb);
    float4 ab = *(const float4*)(par + P_ATT1 + chb + 4);
    a2[0].x = aa.x; a2[0].y = aa.y; a2[1].x = aa.z; a2[1].y = aa.w;
    a2[2].x = ab.x; a2[2].y = ab.y; a2[3].x = ab.z; a2[3].y = ab.w;
  }

  const int e0 = offs[dst], e1 = offs[dst + 1];
  const f2 zf2 = {0.f, 0.f};
  f2 acc2[4];
#pragma unroll
  for (int j = 0; j < 4; j++) acc2[j] = zf2;
  float denom = 0.f;

  const uint4 zq = {0, 0, 0, 0};
  // prime a 2-deep pipeline: edges e0+g, e0+g+2 in flight
  int eA = e0 + g, eB = e0 + g + 2;
  bool vA = eA < e1, vB = eB < e1;
  uint4 qA = vA ? *(const uint4*)(xl1 + (size_t)csr[eA] * F1 + chb) : zq;
  uint4 qB = vB ? *(const uint4*)(xl1 + (size_t)csr[eB] * F1 + chb) : zq;

  for (int base = e0; base < e1; base += 2) {
    const uint4 qc = qA;
    const bool vc = vA;
    qA = qB; vA = vB;
    int eN = base + g + 4;           // two iterations ahead
    vB = eN < e1;
    qB = vB ? *(const uint4*)(xl1 + (size_t)csr[eN] * F1 + chb) : zq;

    f2 v2[4];
    unpack8bf2(qc, v2);     // invalid -> zeros
    f2 lt2 = zf2;
#pragma unroll
    for (int j = 0; j < 4; j++)
      lt2 = lrelu2(v2[j] + r2[j]) * a2[j] + lt2;
    float lt = vc ? (lt2.x + lt2.y) : -1e30f;
    // per-head reduce over this lane's 8-lane head subgroup
    lt += __shfl_xor(lt, 1, 64);
    lt += __shfl_xor(lt, 2, 64);
    lt += __shfl_xor(lt, 4, 64);
    float p = __expf(fminf(lt, 60.f));   // logits O(1); invalid group -> 0
    denom += p;
    f2 pv; pv.x = p; pv.y = p;
#pragma unroll
    for (int j = 0; j < 4; j++) acc2[j] = pv * v2[j] + acc2[j];
  }

  // combine the 2 edge groups (lane ^ 32 has same channels & head)
  denom += __shfl_xor(denom, 32, 64);
#pragma unroll
  for (int j = 0; j < 4; j++) {
    acc2[j].x += __shfl_xor(acc2[j].x, 32, 64);
    acc2[j].y += __shfl_xor(acc2[j].y, 32, 64);
  }

  if (g == 0) {
    float inv = 1.f / (denom + EPS_A);
    __align__(16) bf16 ob[8];
#pragma unroll
    for (int j = 0; j < 4; j++) {
      float o0 = fmaxf(acc2[j].x * inv + par[P_BIAS1 + chb + 2*j],     0.f);
      float o1 = fmaxf(acc2[j].y * inv + par[P_BIAS1 + chb + 2*j + 1], 0.f);
      ob[2*j] = (bf16)o0; ob[2*j+1] = (bf16)o1;
    }
    *(uint4*)(hout + (size_t)dst * F1 + chb) = *(uint4*)ob;
  }
}

// ---------------- layer-2 aggregation: one wave per dst, 4 groups x 16 lanes,
// 8 ch/lane, 2-deep register prefetch ----------------
__global__ __launch_bounds__(256, 8) void agg2_k(
    const bf16* __restrict__ xl2, const bf16* __restrict__ xr2,
    const float* __restrict__ par,
    const int* __restrict__ offs, const int* __restrict__ csr,
    bf16* __restrict__ h2) {
  const int dst = blockIdx.x * 4 + (threadIdx.x >> 6);
  if (dst >= N_NODES) return;
  const int lane = threadIdx.x & 63;
  const int g = lane >> 4;        // 4 edge groups
  const int sl = lane & 15;
  const int chb = sl * 8;

  f2 r2[4], a2[4];
  load8bf2(xr2 + (size_t)dst * F2 + chb, r2);
  {
    float4 aa = *(const float4*)(par + P_ATT2 + chb);
    float4 ab = *(const float4*)(par + P_ATT2 + chb + 4);
    a2[0].x = aa.x; a2[0].y = aa.y; a2[1].x = aa.z; a2[1].y = aa.w;
    a2[2].x = ab.x; a2[2].y = ab.y; a2[3].x = ab.z; a2[3].y = ab.w;
  }

  const int e0 = offs[dst], e1 = offs[dst + 1];
  const f2 zf2 = {0.f, 0.f};
  f2 acc2[4];
#pragma unroll
  for (int j = 0; j < 4; j++) acc2[j] = zf2;
  float denom = 0.f;

  const uint4 zq = {0, 0, 0, 0};
  int eA = e0 + g, eB = e0 + g + 4;
  bool vA = eA < e1, vB = eB < e1;
  uint4 qA = vA ? *(const uint4*)(xl2 + (size_t)csr[eA] * F2 + chb) : zq;
  uint4 qB = vB ? *(const uint4*)(xl2 + (size_t)csr[eB] * F2 + chb) : zq;

  for (int base = e0; base < e1; base += 4) {
    const uint4 qc = qA;
    const bool vc = vA;
    qA = qB; vA = vB;
    int eN = base + g + 8;
    vB = eN < e1;
    qB = vB ? *(const uint4*)(xl2 + (size_t)csr[eN] * F2 + chb) : zq;

    f2 v2[4];
    unpack8bf2(qc, v2);
    f2 lt2 = zf2;
#pragma unroll
    for (int j = 0; j < 4; j++)
      lt2 = lrelu2(v2[j] + r2[j]) * a2[j] + lt2;
    float lt = vc ? (lt2.x + lt2.y) : -1e30f;
    // reduce over the 16-lane group
    lt += __shfl_xor(lt, 1, 64);
    lt += __shfl_xor(lt, 2, 64);
    lt += __shfl_xor(lt, 4, 64);
    lt += __shfl_xor(lt, 8, 64);
    float p = __expf(fminf(lt, 60.f));
    denom += p;
    f2 pv; pv.x = p; pv.y = p;
#pragma unroll
    for (int j = 0; j < 4; j++) acc2[j] = pv * v2[j] + acc2[j];
  }

  // combine the 4 edge groups (lanes ^16 / ^32 share channels)
#pragma unroll
  for (int m = 16; m <= 32; m <<= 1) {
    denom += __shfl_xor(denom, m, 64);
#pragma unroll
    for (int j = 0; j < 4; j++) {
      acc2[j].x += __shfl_xor(acc2[j].x, m, 64);
      acc2[j].y += __shfl_xor(acc2[j].y, m, 64);
    }
  }

  if (g == 0) {
    float inv = 1.f / (denom + EPS_A);
    __align__(16) bf16 ob[8];
#pragma unroll
    for (int j = 0; j < 4; j++) {
      float o0 = fmaxf(acc2[j].x * inv + par[P_BIAS2 + chb + 2*j],     0.f);
      float o1 = fmaxf(acc2[j].y * inv + par[P_BIAS2 + chb + 2*j + 1], 0.f);
      ob[2*j] = (bf16)o0; ob[2*j+1] = (bf16)o1;
    }
    *(uint4*)(h2 + (size_t)dst * F2 + chb) = *(uint4*)ob;
  }
}

// ---------------- pooling ----------------
__global__ __launch_bounds__(256) void pool_k(
    const bf16* __restrict__ h2, const int* __restrict__ gs,
    const int* __restrict__ ge, const void* __restrict__ x,
    void* __restrict__ out) {
  const int flag = detect_f32_wave(x);
  const int g = blockIdx.x;
  const int t = threadIdx.x;
  const int c = t & 127, half = t >> 7;
  int s = gs[g], e = ge[g];
  if (s < 0 || e < s) { s = 0; e = -1; }   // empty graph (memset-init) -> 0
  float sum = 0.f;
  for (int n = s + half; n <= e; n += 2)
    sum += (float)h2[(size_t)n * F2 + c];
  __shared__ float red[128];
  if (half == 1) red[c] = sum;
  __syncthreads();
  if (half == 0) {
    float tot = sum + red[c];
    float cnt = (e >= s) ? (float)(e - s + 1) : 1.f;
    float v = tot / cnt;
    if (flag) ((float*)out)[g * F2 + c] = v;
    else      ((bf16*)out)[g * F2 + c] = (bf16)v;
  }
}

// ---------------- launch ----------------
extern "C" void kernel_launch(void* const* d_in, const int* in_sizes, int n_in,
                              void* d_out, int out_size, void* d_ws, size_t ws_size,
                              hipStream_t stream) {
  (void)in_sizes; (void)n_in; (void)out_size; (void)ws_size;
  const void* x     = d_in[0];
  const int*  ei    = (const int*)d_in[1];
  const int*  batch = (const int*)d_in[2];

  char* ws = (char*)d_ws;
  float* par  = (float*)(ws + OFF_PAR);
  bf16* xl1 = (bf16*)(ws + OFF_XL1);
  bf16* xr1 = (bf16*)(ws + OFF_XR1);
  bf16* h   = (bf16*)(ws + OFF_H);
  bf16* xl2 = (bf16*)(ws + OFF_XL2);
  bf16* xr2 = (bf16*)(ws + OFF_XR2);
  bf16* h2  = (bf16*)(ws + OFF_H2);
  bf16* xb  = (bf16*)(ws + OFF_XB);
  bf16* wt1 = (bf16*)(ws + OFF_WT1);
  bf16* wt2 = (bf16*)(ws + OFF_WT2);
  int* cnt    = (int*)(ws + OFF_CNT);
  int* offs   = (int*)(ws + OFF_OFFS);
  int* csr    = (int*)(ws + OFF_CSR);
  int* gs     = (int*)(ws + OFF_GS);
  int* ge     = (int*)(ws + OFF_GE);
  int* bsum   = (int*)(ws + OFF_BS);
  int* rank   = (int*)(ws + OFF_RANK);

  hipMemsetAsync(cnt, 0, (size_t)N_NODES * 4, stream);
  hipMemsetAsync(gs, 0xFF, (size_t)(OFF_WT1 - OFF_GS), stream);  // gs/ge = -1

  PrepArgs pa;
  pa.x = x; pa.ei = ei; pa.batch = batch;
  for (int i = 0; i < 12; i++) pa.src[i] = d_in[3 + i];
  const int prep_blocks = B_CVT + B_XP + B_W1 + B_W2 + B_BND + B_CNT;
  prep_k<<<prep_blocks, 256, 0, stream>>>(pa, par, xb, wt1, wt2, gs, ge, cnt, rank);

  scan_a<<<SCAN_BLKS, 1024, 0, stream>>>(cnt, offs, bsum);
  scan_c<<<(N_NODES + 255) / 256, 256, 0, stream>>>(bsum, offs);

  gemm1_scatter_k<<<GBLK + SBL, 256, 0, stream>>>(xb, wt1, par, xl1, xr1,
                                                  ei, offs, rank, csr);
  agg1_k<<<(N_NODES + 3) / 4, 256, 0, stream>>>(xl1, xr1, par, offs, csr, h);
  gemm2_mfma_k<<<GBLK, 256, 0, stream>>>(h, wt2, par, xl2, xr2);
  agg2_k<<<(N_NODES + 3) / 4, 256, 0, stream>>>(xl2, xr2, par, offs, csr, h2);
  pool_k<<<NGRAPH, 256, 0, stream>>>(h2, gs, ge, x, d_out);
}

// Round 14
// 383.627 us; speedup vs baseline: 1.0594x; 1.0594x over previous
//
#include <hip/hip_runtime.h>
#include <hip/hip_bf16.h>
#include <limits.h>

// ---------------- problem constants ----------------
#define N_NODES 50000
#define N_EDGES 800000
#define TOT_E   (N_EDGES + N_NODES)   // with self loops
#define IN_F    38
#define HIDC    64
#define NH      4
#define F1      256                    // NH*HIDC
#define F2      128                    // OUT
#define NGRAPH  128
#define NEG_SLOPE 0.2f
#define EPS_A   1e-16f

typedef __hip_bfloat16 bf16;
typedef unsigned char fp8_t;           // OCP e4m3 raw byte
typedef __attribute__((ext_vector_type(8))) short short8;
typedef __attribute__((ext_vector_type(16))) float f32x16;
typedef __attribute__((ext_vector_type(2))) float f2;   // lowers to VOP3P v_pk_*_f32

// ---------------- ws layout ----------------
constexpr size_t al256(size_t x) { return (x + 255) & ~(size_t)255; }

// converted-params element offsets (f32 elements)
#define P_WL1   0
#define P_BL1   (P_WL1 + IN_F * F1)
#define P_WR1   (P_BL1 + F1)
#define P_BR1   (P_WR1 + IN_F * F1)
#define P_ATT1  (P_BR1 + F1)
#define P_BIAS1 (P_ATT1 + F1)
#define P_WL2   (P_BIAS1 + F1)
#define P_BL2   (P_WL2 + F1 * F2)
#define P_WR2   (P_BL2 + F2)
#define P_BR2   (P_WR2 + F1 * F2)
#define P_ATT2  (P_BR2 + F2)
#define P_BIAS2 (P_ATT2 + F2)
#define P_TOTAL (P_BIAS2 + F2)         // 86528 = 338*256

constexpr size_t OFF_PAR  = 256;
constexpr size_t OFF_XL1  = OFF_PAR + al256((size_t)P_TOTAL * 4);   // fp8 N*256; reused as h2
constexpr size_t OFF_XR1  = OFF_XL1 + al256((size_t)N_NODES * F1 * 2);
constexpr size_t OFF_H    = OFF_XR1 + al256((size_t)N_NODES * F1 * 2);
constexpr size_t OFF_XL2  = OFF_H   + al256((size_t)N_NODES * F1 * 2);  // fp8 N*128
constexpr size_t OFF_XR2  = OFF_XL2 + al256((size_t)N_NODES * F2 * 2);
constexpr size_t OFF_CNT  = OFF_XR2 + al256((size_t)N_NODES * F2 * 2);
constexpr size_t OFF_OFFS = OFF_CNT + al256((size_t)N_NODES * 4);
constexpr size_t OFF_CSR  = OFF_OFFS+ al256((size_t)(N_NODES + 1) * 4);
constexpr size_t OFF_GS   = OFF_CSR + al256((size_t)TOT_E * 4);
constexpr size_t OFF_GE   = OFF_GS  + al256((size_t)NGRAPH * 4);
constexpr size_t OFF_WT1  = OFF_GE  + al256((size_t)NGRAPH * 4);    // 512x64 bf16
constexpr size_t OFF_WT2  = OFF_WT1 + al256((size_t)512 * 64 * 2);  // 256x256 bf16
constexpr size_t OFF_BS   = OFF_WT2 + al256((size_t)256 * 256 * 2); // 49 block sums
constexpr size_t OFF_RANK = OFF_BS  + al256(64 * 4);                // per-edge rank
constexpr size_t OFF_H2   = OFF_XL1;  // xl1 dead after agg1
constexpr size_t OFF_XB   = OFF_H;    // xb dead before agg1 writes h

#define SCAN_BLKS 49   // ceil(50000/1024)
#define GBLK 1563      // ceil(50000/32)
#define SBL  831       // ceil(TOT_E/1024)

// ---------------- helpers ----------------
__device__ __forceinline__ void unpack8bf2(uint4 q, f2* f) {
  unsigned v[4] = {q.x, q.y, q.z, q.w};
#pragma unroll
  for (int i = 0; i < 4; i++) {
    f2 t;
    t.x = __uint_as_float(v[i] << 16);
    t.y = __uint_as_float(v[i] & 0xffff0000u);
    f[i] = t;
  }
}

__device__ __forceinline__ void load8bf2(const bf16* __restrict__ p, f2* f) {
  unpack8bf2(*(const uint4*)p, f);
}

// 8 fp8 bytes -> 4 x f2 via HW v_cvt_pk_f32_fp8 (2 ch / inst)
__device__ __forceinline__ void unpack8fp8(uint2 q, f2* f) {
  f[0] = __builtin_amdgcn_cvt_pk_f32_fp8(q.x, false);
  f[1] = __builtin_amdgcn_cvt_pk_f32_fp8(q.x, true);
  f[2] = __builtin_amdgcn_cvt_pk_f32_fp8(q.y, false);
  f[3] = __builtin_amdgcn_cvt_pk_f32_fp8(q.y, true);
}

__device__ __forceinline__ fp8_t f32_to_fp8(float v) {
  return (fp8_t)(__builtin_amdgcn_cvt_pk_fp8_f32(v, v, 0, false) & 0xFF);
}

// leaky_relu(s) = 0.6*s + 0.4*|s|
__device__ __forceinline__ f2 lrelu2(f2 s) {
  f2 as;
  as.x = __uint_as_float(__float_as_uint(s.x) & 0x7fffffffu);
  as.y = __uint_as_float(__float_as_uint(s.y) & 0x7fffffffu);
  return 0.6f * s + 0.4f * as;
}

// wave-cooperative dtype sniff: 1 = inputs are f32, 0 = bf16.
__device__ __forceinline__ int detect_f32_wave(const void* __restrict__ x) {
  const unsigned short* u = (const unsigned short*)x;
  unsigned short b = u[threadIdx.x & 63];
  int e = (b >> 7) & 0xFF;
  unsigned long long m = __ballot(!((e == 0) || (e >= 96 && e <= 158)));
  return __popcll(m) > 8;
}

// ---------------- fused prep kernel ----------------
#define B_CVT  338
#define B_XP   12500
#define B_W1   128
#define B_W2   256
#define B_BND  196
#define B_CNT  3321

struct PrepArgs {
  const void* x;
  const void* src[12];
  const int* ei;
  const int* batch;
};

__global__ __launch_bounds__(256) void prep_k(
    PrepArgs a, float* __restrict__ par, bf16* __restrict__ xb,
    bf16* __restrict__ wt1, bf16* __restrict__ wt2,
    int* __restrict__ gs, int* __restrict__ ge, int* __restrict__ cnt,
    int* __restrict__ rank) {
  int b = blockIdx.x;
  const int tid = threadIdx.x;

  if (b < B_CVT) {                       // ---- param convert -> f32 ----
    const int flag = detect_f32_wave(a.x);
    int idx = b * 256 + tid;
    const void* p; int base;
    if      (idx < P_BL1)  { p = a.src[0];  base = P_WL1; }
    else if (idx < P_WR1)  { p = a.src[1];  base = P_BL1; }
    else if (idx < P_BR1)  { p = a.src[2];  base = P_WR1; }
    else if (idx < P_ATT1) { p = a.src[3];  base = P_BR1; }
    else if (idx < P_BIAS1){ p = a.src[4];  base = P_ATT1; }
    else if (idx < P_WL2)  { p = a.src[5];  base = P_BIAS1; }
    else if (idx < P_BL2)  { p = a.src[6];  base = P_WL2; }
    else if (idx < P_WR2)  { p = a.src[7];  base = P_BL2; }
    else if (idx < P_BR2)  { p = a.src[8];  base = P_WR2; }
    else if (idx < P_ATT2) { p = a.src[9];  base = P_BR2; }
    else if (idx < P_BIAS2){ p = a.src[10]; base = P_ATT2; }
    else                   { p = a.src[11]; base = P_BIAS2; }
    int li = idx - base;
    par[idx] = flag ? ((const float*)p)[li] : (float)((const bf16*)p)[li];
    return;
  }
  b -= B_CVT;
  if (b < B_XP) {                        // ---- x -> xb (N x 64, zero-pad K) ----
    const int flag = detect_f32_wave(a.x);
    int i = b * 256 + tid;
    int n = i >> 6, k = i & 63;
    float v = 0.f;
    if (k < IN_F) {
      int idx = n * IN_F + k;
      v = flag ? ((const float*)a.x)[idx] : (float)((const bf16*)a.x)[idx];
    }
    xb[i] = (bf16)v;
    return;
  }
  b -= B_XP;
  if (b < B_W1) {                        // ---- Wt1[n][k] 512x64 ----
    const int flag = detect_f32_wave(a.x);
    int i = b * 256 + tid;
    int n = i >> 6, k = i & 63;
    float v = 0.f;
    if (k < IN_F) {
      const void* W = (n < F1) ? a.src[0] : a.src[2];
      int col = (n < F1) ? n : n - F1;
      int idx = k * F1 + col;
      v = flag ? ((const float*)W)[idx] : (float)((const bf16*)W)[idx];
    }
    wt1[i] = (bf16)v;
    return;
  }
  b -= B_W1;
  if (b < B_W2) {                        // ---- Wt2[n][k] 256x256 ----
    const int flag = detect_f32_wave(a.x);
    int i = b * 256 + tid;
    int n = i >> 8, k = i & 255;
    const void* W = (n < F2) ? a.src[6] : a.src[8];
    int col = (n < F2) ? n : n - F2;
    int idx = k * F2 + col;
    float v = flag ? ((const float*)W)[idx] : (float)((const bf16*)W)[idx];
    wt2[i] = (bf16)v;
    return;
  }
  b -= B_W2;
  if (b < B_BND) {                       // ---- graph bounds (batch sorted) ----
    int n = b * 256 + tid;
    if (n >= N_NODES) return;
    int bb = a.batch[n];
    if (n == 0) gs[bb] = 0;
    else {
      int bp = a.batch[n - 1];
      if (bp != bb) { gs[bb] = n; ge[bp] = n - 1; }
    }
    if (n == N_NODES - 1) ge[bb] = N_NODES - 1;
    return;
  }
  b -= B_BND;
  {                                      // ---- degree count + per-edge rank ----
    int e = b * 256 + tid;
    if (e >= TOT_E) return;
    int dst = (e < N_EDGES) ? a.ei[N_EDGES + e] : (e - N_EDGES);
    rank[e] = atomicAdd(&cnt[dst], 1);
  }
}

// ---------------- fused: GEMM1 (MFMA 32x32x16) || atomic-free scatter ----------------
// xl1 written as fp8 e4m3 (gather table); xr1 stays bf16 (contiguous dst read).
__global__ __launch_bounds__(256) void gemm1_scatter_k(
    const bf16* __restrict__ xb, const bf16* __restrict__ wt1,
    const float* __restrict__ par,
    fp8_t* __restrict__ xl1, bf16* __restrict__ xr1,
    const int* __restrict__ ei, const int* __restrict__ offs,
    const int* __restrict__ rank, int* __restrict__ csr) {
  if (blockIdx.x >= GBLK) {              // ---- scatter path ----
    int base = (blockIdx.x - GBLK) * 1024 + threadIdx.x;
#pragma unroll
    for (int i = 0; i < 4; i++) {
      int e = base + i * 256;
      if (e >= TOT_E) continue;
      int src, dst;
      if (e < N_EDGES) { src = ei[e]; dst = ei[N_EDGES + e]; }
      else             { src = dst = e - N_EDGES; }
      csr[offs[dst] + rank[e]] = src;
    }
    return;
  }
  // ---- gemm1 path: 32x32x16 MFMA. Wave w: rows blk*32..+31, cols w*128..+127 ----
  const int w = threadIdx.x >> 6, lane = threadIdx.x & 63;
  const int m0 = blockIdx.x * 32;
  const int colbase = w * 128;
  const int lm = lane & 31;
  const int kh = lane >> 5;

  int arow = m0 + lm; if (arow >= N_NODES) arow = N_NODES - 1;
  short8 afr[4];
#pragma unroll
  for (int kk = 0; kk < 4; kk++)
    afr[kk] = *(const short8*)(xb + (size_t)arow * 64 + kk * 16 + kh * 8);

  f32x16 acc[4] = {};
#pragma unroll
  for (int t = 0; t < 4; t++) {
    int n = colbase + t * 32 + lm;
#pragma unroll
    for (int kk = 0; kk < 4; kk++) {
      short8 b = *(const short8*)(wt1 + (size_t)n * 64 + kk * 16 + kh * 8);
      acc[t] = __builtin_amdgcn_mfma_f32_32x32x16_bf16(afr[kk], b, acc[t], 0, 0, 0);
    }
  }

  // C/D: col = lane&31 (+tile), row = (reg&3) + 8*(reg>>2) + 4*kh
#pragma unroll
  for (int t = 0; t < 4; t++) {
    int col = colbase + t * 32 + lm;
    if (col < F1) {                      // xl1 fp8 (wave-uniform branch)
      float bv = par[P_BL1 + col];
#pragma unroll
      for (int reg = 0; reg < 16; reg++) {
        int row = m0 + (reg & 3) + 8 * (reg >> 2) + 4 * kh;
        if (row < N_NODES)
          xl1[(size_t)row * F1 + col] = f32_to_fp8(acc[t][reg] + bv);
      }
    } else {                             // xr1 bf16
      int c = col - F1;
      float bv = par[P_BR1 + c];
#pragma unroll
      for (int reg = 0; reg < 16; reg++) {
        int row = m0 + (reg & 3) + 8 * (reg >> 2) + 4 * kh;
        if (row < N_NODES)
          xr1[(size_t)row * F1 + c] = (bf16)(acc[t][reg] + bv);
      }
    }
  }
}

// ---------------- GEMM 2 (MFMA 32x32x16): h(N,256) @ Wt2^T -> xl2(fp8)|xr2(bf16) ----------------
__global__ __launch_bounds__(256) void gemm2_mfma_k(
    const bf16* __restrict__ h, const bf16* __restrict__ wt2,
    const float* __restrict__ par,
    fp8_t* __restrict__ xl2, bf16* __restrict__ xr2) {
  const int w = threadIdx.x >> 6, lane = threadIdx.x & 63;
  const int m0 = blockIdx.x * 32;
  const int colbase = w * 64;
  const int lm = lane & 31;
  const int kh = lane >> 5;

  int arow = m0 + lm; if (arow >= N_NODES) arow = N_NODES - 1;
  const bf16* hrow = h + (size_t)arow * F1 + kh * 8;

  f32x16 acc[2] = {};
#pragma unroll
  for (int kk = 0; kk < 16; kk++) {
    short8 a = *(const short8*)(hrow + kk * 16);
#pragma unroll
    for (int t = 0; t < 2; t++) {
      int n = colbase + t * 32 + lm;
      short8 b = *(const short8*)(wt2 + (size_t)n * 256 + kk * 16 + kh * 8);
      acc[t] = __builtin_amdgcn_mfma_f32_32x32x16_bf16(a, b, acc[t], 0, 0, 0);
    }
  }

#pragma unroll
  for (int t = 0; t < 2; t++) {
    int col = colbase + t * 32 + lm;
    if (col < F2) {                      // xl2 fp8
      float bv = par[P_BL2 + col];
#pragma unroll
      for (int reg = 0; reg < 16; reg++) {
        int row = m0 + (reg & 3) + 8 * (reg >> 2) + 4 * kh;
        if (row < N_NODES)
          xl2[(size_t)row * F2 + col] = f32_to_fp8(acc[t][reg] + bv);
      }
    } else {                             // xr2 bf16
      int c = col - F2;
      float bv = par[P_BR2 + c];
#pragma unroll
      for (int reg = 0; reg < 16; reg++) {
        int row = m0 + (reg & 3) + 8 * (reg >> 2) + 4 * kh;
        if (row < N_NODES)
          xr2[(size_t)row * F2 + c] = (bf16)(acc[t][reg] + bv);
      }
    }
  }
}

// ---------------- CSR scan (2-phase) ----------------
__global__ __launch_bounds__(1024) void scan_a(const int* __restrict__ cnt,
                                               int* __restrict__ offs,
                                               int* __restrict__ bsum) {
  __shared__ int wsum[16];
  const int t = threadIdx.x;
  const int lane = t & 63, w = t >> 6;
  int idx = blockIdx.x * 1024 + t;
  int v = (idx < N_NODES) ? cnt[idx] : 0;
  int s = v;
#pragma unroll
  for (int off = 1; off < 64; off <<= 1) {
    int u = __shfl_up(s, off, 64);
    if (lane >= off) s += u;
  }
  if (lane == 63) wsum[w] = s;
  __syncthreads();
  int prefix = 0;
  for (int i = 0; i < w; i++) prefix += wsum[i];
  if (idx < N_NODES) offs[idx] = prefix + s - v;
  if (t == 1023) bsum[blockIdx.x] = prefix + s;
}

__global__ void scan_c(const int* __restrict__ bsum, int* __restrict__ offs) {
  const int t = threadIdx.x;
  const int grp = blockIdx.x >> 2;
  __shared__ int sboff;
  if (t < 64) {
    int v = (t < SCAN_BLKS) ? bsum[t] : 0;
    int s = v;
#pragma unroll
    for (int off = 1; off < 64; off <<= 1) {
      int u = __shfl_up(s, off, 64);
      if (t >= off) s += u;
    }
    if (t == grp) sboff = s - v;
  }
  __syncthreads();
  int idx = blockIdx.x * 256 + t;
  if (idx < N_NODES) offs[idx] += sboff;
  if (blockIdx.x == 0 && t == 0) offs[N_NODES] = TOT_E;
}

// ---------------- layer-1 aggregation: one wave per dst, 2 groups x 32 lanes,
// fp8 gather (8 B/lane), 1-deep register prefetch (the R12-winning shape) ----------------
__global__ __launch_bounds__(256, 4) void agg1_k(
    const fp8_t* __restrict__ xl1, const bf16* __restrict__ xr1,
    const float* __restrict__ par,
    const int* __restrict__ offs, const int* __restrict__ csr,
    bf16* __restrict__ hout) {
  const int dst = blockIdx.x * 4 + (threadIdx.x >> 6);
  if (dst >= N_NODES) return;
  const int lane = threadIdx.x & 63;
  const int g = lane >> 5;        // 2 edge groups
  const int sl = lane & 31;
  const int chb = sl * 8;

  f2 r2[4], a2[4];
  load8bf2(xr1 + (size_t)dst * F1 + chb, r2);
  {
    float4 aa = *(const float4*)(par + P_ATT1 + chb);
    float4 ab = *(const float4*)(par + P_ATT1 + chb + 4);
    a2[0].x = aa.x; a2[0].y = aa.y; a2[1].x = aa.z; a2[1].y = aa.w;
    a2[2].x = ab.x; a2[2].y = ab.y; a2[3].x = ab.z; a2[3].y = ab.w;
  }

  const int e0 = offs[dst], e1 = offs[dst + 1];
  const f2 zf2 = {0.f, 0.f};
  f2 acc2[4];
#pragma unroll
  for (int j = 0; j < 4; j++) acc2[j] = zf2;
  float denom = 0.f;

  const uint2 zq = {0, 0};
  int e = e0 + g;
  bool valid = e < e1;
  uint2 q = valid ? *(const uint2*)(xl1 + (size_t)csr[e] * F1 + chb) : zq;

  for (int base = e0; base < e1; base += 2) {
    const uint2 qc = q;
    const bool vc = valid;
    e += 2;
    valid = e < e1;
    q = valid ? *(const uint2*)(xl1 + (size_t)csr[e] * F1 + chb) : zq;

    f2 v2[4];
    unpack8fp8(qc, v2);     // fp8 0x00 -> 0.0 for invalid
    f2 lt2 = zf2;
#pragma unroll
    for (int j = 0; j < 4; j++)
      lt2 = lrelu2(v2[j] + r2[j]) * a2[j] + lt2;
    float lt = vc ? (lt2.x + lt2.y) : -1e30f;
    lt += __shfl_xor(lt, 1, 64);
    lt += __shfl_xor(lt, 2, 64);
    lt += __shfl_xor(lt, 4, 64);
    float p = __expf(fminf(lt, 60.f));
    denom += p;
    f2 pv; pv.x = p; pv.y = p;
#pragma unroll
    for (int j = 0; j < 4; j++) acc2[j] = pv * v2[j] + acc2[j];
  }

  denom += __shfl_xor(denom, 32, 64);
#pragma unroll
  for (int j = 0; j < 4; j++) {
    acc2[j].x += __shfl_xor(acc2[j].x, 32, 64);
    acc2[j].y += __shfl_xor(acc2[j].y, 32, 64);
  }

  if (g == 0) {
    float inv = 1.f / (denom + EPS_A);
    __align__(16) bf16 ob[8];
#pragma unroll
    for (int j = 0; j < 4; j++) {
      float o0 = fmaxf(acc2[j].x * inv + par[P_BIAS1 + chb + 2*j],     0.f);
      float o1 = fmaxf(acc2[j].y * inv + par[P_BIAS1 + chb + 2*j + 1], 0.f);
      ob[2*j] = (bf16)o0; ob[2*j+1] = (bf16)o1;
    }
    *(uint4*)(hout + (size_t)dst * F1 + chb) = *(uint4*)ob;
  }
}

// ---------------- layer-2 aggregation: one wave per dst, 4 groups x 16 lanes,
// fp8 gather (8 B/lane), 1-deep prefetch ----------------
__global__ __launch_bounds__(256, 4) void agg2_k(
    const fp8_t* __restrict__ xl2, const bf16* __restrict__ xr2,
    const float* __restrict__ par,
    const int* __restrict__ offs, const int* __restrict__ csr,
    bf16* __restrict__ h2) {
  const int dst = blockIdx.x * 4 + (threadIdx.x >> 6);
  if (dst >= N_NODES) return;
  const int lane = threadIdx.x & 63;
  const int g = lane >> 4;        // 4 edge groups
  const int sl = lane & 15;
  const int chb = sl * 8;

  f2 r2[4], a2[4];
  load8bf2(xr2 + (size_t)dst * F2 + chb, r2);
  {
    float4 aa = *(const float4*)(par + P_ATT2 + chb);
    float4 ab = *(const float4*)(par + P_ATT2 + chb + 4);
    a2[0].x = aa.x; a2[0].y = aa.y; a2[1].x = aa.z; a2[1].y = aa.w;
    a2[2].x = ab.x; a2[2].y = ab.y; a2[3].x = ab.z; a2[3].y = ab.w;
  }

  const int e0 = offs[dst], e1 = offs[dst + 1];
  const f2 zf2 = {0.f, 0.f};
  f2 acc2[4];
#pragma unroll
  for (int j = 0; j < 4; j++) acc2[j] = zf2;
  float denom = 0.f;

  const uint2 zq = {0, 0};
  int e = e0 + g;
  bool valid = e < e1;
  uint2 q = valid ? *(const uint2*)(xl2 + (size_t)csr[e] * F2 + chb) : zq;

  for (int base = e0; base < e1; base += 4) {
    const uint2 qc = q;
    const bool vc = valid;
    e += 4;
    valid = e < e1;
    q = valid ? *(const uint2*)(xl2 + (size_t)csr[e] * F2 + chb) : zq;

    f2 v2[4];
    unpack8fp8(qc, v2);
    f2 lt2 = zf2;
#pragma unroll
    for (int j = 0; j < 4; j++)
      lt2 = lrelu2(v2[j] + r2[j]) * a2[j] + lt2;
    float lt = vc ? (lt2.x + lt2.y) : -1e30f;
    lt += __shfl_xor(lt, 1, 64);
    lt += __shfl_xor(lt, 2, 64);
    lt += __shfl_xor(lt, 4, 64);
    lt += __shfl_xor(lt, 8, 64);
    float p = __expf(fminf(lt, 60.f));
    denom += p;
    f2 pv; pv.x = p; pv.y = p;
#pragma unroll
    for (int j = 0; j < 4; j++) acc2[j] = pv * v2[j] + acc2[j];
  }

#pragma unroll
  for (int m = 16; m <= 32; m <<= 1) {
    denom += __shfl_xor(denom, m, 64);
#pragma unroll
    for (int j = 0; j < 4; j++) {
      acc2[j].x += __shfl_xor(acc2[j].x, m, 64);
      acc2[j].y += __shfl_xor(acc2[j].y, m, 64);
    }
  }

  if (g == 0) {
    float inv = 1.f / (denom + EPS_A);
    __align__(16) bf16 ob[8];
#pragma unroll
    for (int j = 0; j < 4; j++) {
      float o0 = fmaxf(acc2[j].x * inv + par[P_BIAS2 + chb + 2*j],     0.f);
      float o1 = fmaxf(acc2[j].y * inv + par[P_BIAS2 + chb + 2*j + 1], 0.f);
      ob[2*j] = (bf16)o0; ob[2*j+1] = (bf16)o1;
    }
    *(uint4*)(h2 + (size_t)dst * F2 + chb) = *(uint4*)ob;
  }
}

// ---------------- pooling ----------------
__global__ __launch_bounds__(256) void pool_k(
    const bf16* __restrict__ h2, const int* __restrict__ gs,
    const int* __restrict__ ge, const void* __restrict__ x,
    void* __restrict__ out) {
  const int flag = detect_f32_wave(x);
  const int g = blockIdx.x;
  const int t = threadIdx.x;
  const int c = t & 127, half = t >> 7;
  int s = gs[g], e = ge[g];
  if (s < 0 || e < s) { s = 0; e = -1; }
  float sum = 0.f;
  for (int n = s + half; n <= e; n += 2)
    sum += (float)h2[(size_t)n * F2 + c];
  __shared__ float red[128];
  if (half == 1) red[c] = sum;
  __syncthreads();
  if (half == 0) {
    float tot = sum + red[c];
    float cnt = (e >= s) ? (float)(e - s + 1) : 1.f;
    float v = tot / cnt;
    if (flag) ((float*)out)[g * F2 + c] = v;
    else      ((bf16*)out)[g * F2 + c] = (bf16)v;
  }
}

// ---------------- launch ----------------
extern "C" void kernel_launch(void* const* d_in, const int* in_sizes, int n_in,
                              void* d_out, int out_size, void* d_ws, size_t ws_size,
                              hipStream_t stream) {
  (void)in_sizes; (void)n_in; (void)out_size; (void)ws_size;
  const void* x     = d_in[0];
  const int*  ei    = (const int*)d_in[1];
  const int*  batch = (const int*)d_in[2];

  char* ws = (char*)d_ws;
  float* par  = (float*)(ws + OFF_PAR);
  fp8_t* xl1 = (fp8_t*)(ws + OFF_XL1);
  bf16* xr1 = (bf16*)(ws + OFF_XR1);
  bf16* h   = (bf16*)(ws + OFF_H);
  fp8_t* xl2 = (fp8_t*)(ws + OFF_XL2);
  bf16* xr2 = (bf16*)(ws + OFF_XR2);
  bf16* h2  = (bf16*)(ws + OFF_H2);
  bf16* xb  = (bf16*)(ws + OFF_XB);
  bf16* wt1 = (bf16*)(ws + OFF_WT1);
  bf16* wt2 = (bf16*)(ws + OFF_WT2);
  int* cnt    = (int*)(ws + OFF_CNT);
  int* offs   = (int*)(ws + OFF_OFFS);
  int* csr    = (int*)(ws + OFF_CSR);
  int* gs     = (int*)(ws + OFF_GS);
  int* ge     = (int*)(ws + OFF_GE);
  int* bsum   = (int*)(ws + OFF_BS);
  int* rank   = (int*)(ws + OFF_RANK);

  hipMemsetAsync(cnt, 0, (size_t)N_NODES * 4, stream);
  hipMemsetAsync(gs, 0xFF, (size_t)(OFF_WT1 - OFF_GS), stream);  // gs/ge = -1

  PrepArgs pa;
  pa.x = x; pa.ei = ei; pa.batch = batch;
  for (int i = 0; i < 12; i++) pa.src[i] = d_in[3 + i];
  const int prep_blocks = B_CVT + B_XP + B_W1 + B_W2 + B_BND + B_CNT;
  prep_k<<<prep_blocks, 256, 0, stream>>>(pa, par, xb, wt1, wt2, gs, ge, cnt, rank);

  scan_a<<<SCAN_BLKS, 1024, 0, stream>>>(cnt, offs, bsum);
  scan_c<<<(N_NODES + 255) / 256, 256, 0, stream>>>(bsum, offs);

  gemm1_scatter_k<<<GBLK + SBL, 256, 0, stream>>>(xb, wt1, par, xl1, xr1,
                                                  ei, offs, rank, csr);
  agg1_k<<<(N_NODES + 3) / 4, 256, 0, stream>>>(xl1, xr1, par, offs, csr, h);
  gemm2_mfma_k<<<GBLK, 256, 0, stream>>>(h, wt2, par, xl2, xr2);
  agg2_k<<<(N_NODES + 3) / 4, 256, 0, stream>>>(xl2, xr2, par, offs, csr, h2);
  pool_k<<<NGRAPH, 256, 0, stream>>>(h2, gs, ge, x, d_out);
}

// Round 15
// 381.770 us; speedup vs baseline: 1.0645x; 1.0049x over previous
//
#include <hip/hip_runtime.h>
#include <hip/hip_bf16.h>
#include <limits.h>

// ---------------- problem constants ----------------
#define N_NODES 50000
#define N_EDGES 800000
#define TOT_E   (N_EDGES + N_NODES)   // with self loops
#define IN_F    38
#define HIDC    64
#define NH      4
#define F1      256                    // NH*HIDC
#define F2      128                    // OUT
#define NGRAPH  128
#define NEG_SLOPE 0.2f
#define EPS_A   1e-16f

typedef __hip_bfloat16 bf16;
typedef unsigned char fp8_t;           // OCP e4m3 raw byte
typedef __attribute__((ext_vector_type(8))) short short8;
typedef __attribute__((ext_vector_type(16))) float f32x16;
typedef __attribute__((ext_vector_type(2))) float f2;   // lowers to VOP3P v_pk_*_f32

// ---------------- ws layout ----------------
constexpr size_t al256(size_t x) { return (x + 255) & ~(size_t)255; }

// converted-params element offsets (f32 elements)
#define P_WL1   0
#define P_BL1   (P_WL1 + IN_F * F1)
#define P_WR1   (P_BL1 + F1)
#define P_BR1   (P_WR1 + IN_F * F1)
#define P_ATT1  (P_BR1 + F1)
#define P_BIAS1 (P_ATT1 + F1)
#define P_WL2   (P_BIAS1 + F1)
#define P_BL2   (P_WL2 + F1 * F2)
#define P_WR2   (P_BL2 + F2)
#define P_BR2   (P_WR2 + F1 * F2)
#define P_ATT2  (P_BR2 + F2)
#define P_BIAS2 (P_ATT2 + F2)
#define P_TOTAL (P_BIAS2 + F2)         // 86528 = 338*256

constexpr size_t OFF_PAR  = 256;
constexpr size_t OFF_XL1  = OFF_PAR + al256((size_t)P_TOTAL * 4);   // fp8 N*256; reused as h2
constexpr size_t OFF_XR1  = OFF_XL1 + al256((size_t)N_NODES * F1 * 2);
constexpr size_t OFF_H    = OFF_XR1 + al256((size_t)N_NODES * F1 * 2);
constexpr size_t OFF_XL2  = OFF_H   + al256((size_t)N_NODES * F1 * 2);  // fp8 N*128
constexpr size_t OFF_XR2  = OFF_XL2 + al256((size_t)N_NODES * F2 * 2);
constexpr size_t OFF_CNT  = OFF_XR2 + al256((size_t)N_NODES * F2 * 2);
constexpr size_t OFF_OFFS = OFF_CNT + al256((size_t)N_NODES * 4);
constexpr size_t OFF_CSR  = OFF_OFFS+ al256((size_t)(N_NODES + 1) * 4);
constexpr size_t OFF_GS   = OFF_CSR + al256((size_t)TOT_E * 4);
constexpr size_t OFF_GE   = OFF_GS  + al256((size_t)NGRAPH * 4);
constexpr size_t OFF_WT1  = OFF_GE  + al256((size_t)NGRAPH * 4);    // 512x64 bf16
constexpr size_t OFF_WT2  = OFF_WT1 + al256((size_t)512 * 64 * 2);  // 256x256 bf16
constexpr size_t OFF_BS   = OFF_WT2 + al256((size_t)256 * 256 * 2); // 49 block sums
constexpr size_t OFF_RANK = OFF_BS  + al256(64 * 4);                // per-edge rank
constexpr size_t OFF_H2   = OFF_XL1;  // xl1 dead after agg1
constexpr size_t OFF_XB   = OFF_H;    // xb dead before agg1 writes h

#define SCAN_BLKS 49   // ceil(50000/1024)
#define GBLK 1563      // ceil(50000/32)
#define SBL  831       // ceil(TOT_E/1024)

// ---------------- helpers ----------------
__device__ __forceinline__ void unpack8bf2(uint4 q, f2* f) {
  unsigned v[4] = {q.x, q.y, q.z, q.w};
#pragma unroll
  for (int i = 0; i < 4; i++) {
    f2 t;
    t.x = __uint_as_float(v[i] << 16);
    t.y = __uint_as_float(v[i] & 0xffff0000u);
    f[i] = t;
  }
}

__device__ __forceinline__ void load8bf2(const bf16* __restrict__ p, f2* f) {
  unpack8bf2(*(const uint4*)p, f);
}

// 8 fp8 bytes -> 4 x f2 via HW v_cvt_pk_f32_fp8
__device__ __forceinline__ void unpack8fp8(uint2 q, f2* f) {
  f[0] = __builtin_amdgcn_cvt_pk_f32_fp8(q.x, false);
  f[1] = __builtin_amdgcn_cvt_pk_f32_fp8(q.x, true);
  f[2] = __builtin_amdgcn_cvt_pk_f32_fp8(q.y, false);
  f[3] = __builtin_amdgcn_cvt_pk_f32_fp8(q.y, true);
}

__device__ __forceinline__ fp8_t f32_to_fp8(float v) {
  return (fp8_t)(__builtin_amdgcn_cvt_pk_fp8_f32(v, v, 0, false) & 0xFF);
}

// leaky_relu(s) = 0.6*s + 0.4*|s|
__device__ __forceinline__ f2 lrelu2(f2 s) {
  f2 as;
  as.x = __uint_as_float(__float_as_uint(s.x) & 0x7fffffffu);
  as.y = __uint_as_float(__float_as_uint(s.y) & 0x7fffffffu);
  return 0.6f * s + 0.4f * as;
}

// wave-cooperative dtype sniff: 1 = inputs are f32, 0 = bf16.
__device__ __forceinline__ int detect_f32_wave(const void* __restrict__ x) {
  const unsigned short* u = (const unsigned short*)x;
  unsigned short b = u[threadIdx.x & 63];
  int e = (b >> 7) & 0xFF;
  unsigned long long m = __ballot(!((e == 0) || (e >= 96 && e <= 158)));
  return __popcll(m) > 8;
}

// ---------------- fused prep kernel (MLP-widened) ----------------
#define B_CVT  338
#define B_XP   1563    // 8 channels/thread: 50000*8/256
#define B_W1   128
#define B_W2   256
#define B_BND  196
#define B_CNT  831     // 4 edges/thread

struct PrepArgs {
  const void* x;
  const void* src[12];
  const int* ei;
  const int* batch;
};

__global__ __launch_bounds__(256) void prep_k(
    PrepArgs a, float* __restrict__ par, bf16* __restrict__ xb,
    bf16* __restrict__ wt1, bf16* __restrict__ wt2,
    int* __restrict__ gs, int* __restrict__ ge, int* __restrict__ cnt,
    int* __restrict__ rank) {
  int b = blockIdx.x;
  const int tid = threadIdx.x;

  if (b < B_CVT) {                       // ---- param convert -> f32 ----
    const int flag = detect_f32_wave(a.x);
    int idx = b * 256 + tid;
    const void* p; int base;
    if      (idx < P_BL1)  { p = a.src[0];  base = P_WL1; }
    else if (idx < P_WR1)  { p = a.src[1];  base = P_BL1; }
    else if (idx < P_BR1)  { p = a.src[2];  base = P_WR1; }
    else if (idx < P_ATT1) { p = a.src[3];  base = P_BR1; }
    else if (idx < P_BIAS1){ p = a.src[4];  base = P_ATT1; }
    else if (idx < P_WL2)  { p = a.src[5];  base = P_BIAS1; }
    else if (idx < P_BL2)  { p = a.src[6];  base = P_WL2; }
    else if (idx < P_WR2)  { p = a.src[7];  base = P_BL2; }
    else if (idx < P_BR2)  { p = a.src[8];  base = P_WR2; }
    else if (idx < P_ATT2) { p = a.src[9];  base = P_BR2; }
    else if (idx < P_BIAS2){ p = a.src[10]; base = P_ATT2; }
    else                   { p = a.src[11]; base = P_BIAS2; }
    int li = idx - base;
    par[idx] = flag ? ((const float*)p)[li] : (float)((const bf16*)p)[li];
    return;
  }
  b -= B_CVT;
  if (b < B_XP) {                        // ---- x -> xb, 8 ch/thread (8 loads in flight) ----
    const int flag = detect_f32_wave(a.x);
    int gid = b * 256 + tid;             // [0, 50000*8)
    int n = gid >> 3, k0 = (gid & 7) * 8;
    float v[8];
#pragma unroll
    for (int j = 0; j < 8; j++) {
      int k = k0 + j;
      v[j] = 0.f;
      if (k < IN_F) {
        int idx = n * IN_F + k;
        v[j] = flag ? ((const float*)a.x)[idx] : (float)((const bf16*)a.x)[idx];
      }
    }
    __align__(16) bf16 ob[8];
#pragma unroll
    for (int j = 0; j < 8; j++) ob[j] = (bf16)v[j];
    *(uint4*)(xb + (size_t)n * 64 + k0) = *(uint4*)ob;
    return;
  }
  b -= B_XP;
  if (b < B_W1) {                        // ---- Wt1[n][k] 512x64 ----
    const int flag = detect_f32_wave(a.x);
    int i = b * 256 + tid;
    int n = i >> 6, k = i & 63;
    float v = 0.f;
    if (k < IN_F) {
      const void* W = (n < F1) ? a.src[0] : a.src[2];
      int col = (n < F1) ? n : n - F1;
      int idx = k * F1 + col;
      v = flag ? ((const float*)W)[idx] : (float)((const bf16*)W)[idx];
    }
    wt1[i] = (bf16)v;
    return;
  }
  b -= B_W1;
  if (b < B_W2) {                        // ---- Wt2[n][k] 256x256 ----
    const int flag = detect_f32_wave(a.x);
    int i = b * 256 + tid;
    int n = i >> 8, k = i & 255;
    const void* W = (n < F2) ? a.src[6] : a.src[8];
    int col = (n < F2) ? n : n - F2;
    int idx = k * F2 + col;
    float v = flag ? ((const float*)W)[idx] : (float)((const bf16*)W)[idx];
    wt2[i] = (bf16)v;
    return;
  }
  b -= B_W2;
  if (b < B_BND) {                       // ---- graph bounds (batch sorted) ----
    int n = b * 256 + tid;
    if (n >= N_NODES) return;
    int bb = a.batch[n];
    if (n == 0) gs[bb] = 0;
    else {
      int bp = a.batch[n - 1];
      if (bp != bb) { gs[bb] = n; ge[bp] = n - 1; }
    }
    if (n == N_NODES - 1) ge[bb] = N_NODES - 1;
    return;
  }
  b -= B_BND;
  {                                      // ---- degree count + rank, 4 edges/thread ----
    int base = b * 1024 + tid;
    int dstv[4]; bool val[4];
#pragma unroll
    for (int i = 0; i < 4; i++) {
      int e = base + i * 256;
      val[i] = e < TOT_E;
      dstv[i] = 0;
      if (val[i])
        dstv[i] = (e < N_EDGES) ? a.ei[N_EDGES + e] : (e - N_EDGES);
    }
#pragma unroll
    for (int i = 0; i < 4; i++) {        // 4 independent atomics in flight
      int e = base + i * 256;
      if (val[i]) rank[e] = atomicAdd(&cnt[dstv[i]], 1);
    }
  }
}

// ---------------- fused: GEMM1 (MFMA 32x32x16) || atomic-free scatter ----------------
__global__ __launch_bounds__(256) void gemm1_scatter_k(
    const bf16* __restrict__ xb, const bf16* __restrict__ wt1,
    const float* __restrict__ par,
    fp8_t* __restrict__ xl1, bf16* __restrict__ xr1,
    const int* __restrict__ ei, const int* __restrict__ offs,
    const int* __restrict__ rank, int* __restrict__ csr) {
  if (blockIdx.x >= GBLK) {              // ---- scatter path ----
    int base = (blockIdx.x - GBLK) * 1024 + threadIdx.x;
#pragma unroll
    for (int i = 0; i < 4; i++) {
      int e = base + i * 256;
      if (e >= TOT_E) continue;
      int src, dst;
      if (e < N_EDGES) { src = ei[e]; dst = ei[N_EDGES + e]; }
      else             { src = dst = e - N_EDGES; }
      csr[offs[dst] + rank[e]] = src;
    }
    return;
  }
  // ---- gemm1 path ----
  const int w = threadIdx.x >> 6, lane = threadIdx.x & 63;
  const int m0 = blockIdx.x * 32;
  const int colbase = w * 128;
  const int lm = lane & 31;
  const int kh = lane >> 5;

  int arow = m0 + lm; if (arow >= N_NODES) arow = N_NODES - 1;
  short8 afr[4];
#pragma unroll
  for (int kk = 0; kk < 4; kk++)
    afr[kk] = *(const short8*)(xb + (size_t)arow * 64 + kk * 16 + kh * 8);

  f32x16 acc[4] = {};
#pragma unroll
  for (int t = 0; t < 4; t++) {
    int n = colbase + t * 32 + lm;
#pragma unroll
    for (int kk = 0; kk < 4; kk++) {
      short8 b = *(const short8*)(wt1 + (size_t)n * 64 + kk * 16 + kh * 8);
      acc[t] = __builtin_amdgcn_mfma_f32_32x32x16_bf16(afr[kk], b, acc[t], 0, 0, 0);
    }
  }

#pragma unroll
  for (int t = 0; t < 4; t++) {
    int col = colbase + t * 32 + lm;
    if (col < F1) {
      float bv = par[P_BL1 + col];
#pragma unroll
      for (int reg = 0; reg < 16; reg++) {
        int row = m0 + (reg & 3) + 8 * (reg >> 2) + 4 * kh;
        if (row < N_NODES)
          xl1[(size_t)row * F1 + col] = f32_to_fp8(acc[t][reg] + bv);
      }
    } else {
      int c = col - F1;
      float bv = par[P_BR1 + c];
#pragma unroll
      for (int reg = 0; reg < 16; reg++) {
        int row = m0 + (reg & 3) + 8 * (reg >> 2) + 4 * kh;
        if (row < N_NODES)
          xr1[(size_t)row * F1 + c] = (bf16)(acc[t][reg] + bv);
      }
    }
  }
}

// ---------------- GEMM 2 (MFMA 32x32x16) ----------------
__global__ __launch_bounds__(256) void gemm2_mfma_k(
    const bf16* __restrict__ h, const bf16* __restrict__ wt2,
    const float* __restrict__ par,
    fp8_t* __restrict__ xl2, bf16* __restrict__ xr2) {
  const int w = threadIdx.x >> 6, lane = threadIdx.x & 63;
  const int m0 = blockIdx.x * 32;
  const int colbase = w * 64;
  const int lm = lane & 31;
  const int kh = lane >> 5;

  int arow = m0 + lm; if (arow >= N_NODES) arow = N_NODES - 1;
  const bf16* hrow = h + (size_t)arow * F1 + kh * 8;

  f32x16 acc[2] = {};
#pragma unroll
  for (int kk = 0; kk < 16; kk++) {
    short8 a = *(const short8*)(hrow + kk * 16);
#pragma unroll
    for (int t = 0; t < 2; t++) {
      int n = colbase + t * 32 + lm;
      short8 b = *(const short8*)(wt2 + (size_t)n * 256 + kk * 16 + kh * 8);
      acc[t] = __builtin_amdgcn_mfma_f32_32x32x16_bf16(a, b, acc[t], 0, 0, 0);
    }
  }

#pragma unroll
  for (int t = 0; t < 2; t++) {
    int col = colbase + t * 32 + lm;
    if (col < F2) {
      float bv = par[P_BL2 + col];
#pragma unroll
      for (int reg = 0; reg < 16; reg++) {
        int row = m0 + (reg & 3) + 8 * (reg >> 2) + 4 * kh;
        if (row < N_NODES)
          xl2[(size_t)row * F2 + col] = f32_to_fp8(acc[t][reg] + bv);
      }
    } else {
      int c = col - F2;
      float bv = par[P_BR2 + c];
#pragma unroll
      for (int reg = 0; reg < 16; reg++) {
        int row = m0 + (reg & 3) + 8 * (reg >> 2) + 4 * kh;
        if (row < N_NODES)
          xr2[(size_t)row * F2 + c] = (bf16)(acc[t][reg] + bv);
      }
    }
  }
}

// ---------------- CSR scan (2-phase) ----------------
__global__ __launch_bounds__(1024) void scan_a(const int* __restrict__ cnt,
                                               int* __restrict__ offs,
                                               int* __restrict__ bsum) {
  __shared__ int wsum[16];
  const int t = threadIdx.x;
  const int lane = t & 63, w = t >> 6;
  int idx = blockIdx.x * 1024 + t;
  int v = (idx < N_NODES) ? cnt[idx] : 0;
  int s = v;
#pragma unroll
  for (int off = 1; off < 64; off <<= 1) {
    int u = __shfl_up(s, off, 64);
    if (lane >= off) s += u;
  }
  if (lane == 63) wsum[w] = s;
  __syncthreads();
  int prefix = 0;
  for (int i = 0; i < w; i++) prefix += wsum[i];
  if (idx < N_NODES) offs[idx] = prefix + s - v;
  if (t == 1023) bsum[blockIdx.x] = prefix + s;
}

__global__ void scan_c(const int* __restrict__ bsum, int* __restrict__ offs) {
  const int t = threadIdx.x;
  const int grp = blockIdx.x >> 2;
  __shared__ int sboff;
  if (t < 64) {
    int v = (t < SCAN_BLKS) ? bsum[t] : 0;
    int s = v;
#pragma unroll
    for (int off = 1; off < 64; off <<= 1) {
      int u = __shfl_up(s, off, 64);
      if (t >= off) s += u;
    }
    if (t == grp) sboff = s - v;
  }
  __syncthreads();
  int idx = blockIdx.x * 256 + t;
  if (idx < N_NODES) offs[idx] += sboff;
  if (blockIdx.x == 0 && t == 0) offs[N_NODES] = TOT_E;
}

// ---------------- layer-1 aggregation: one wave per dst, 2 groups x 32 lanes,
// PAIRED edges per iteration (2 independent 8B loads in flight) + 1-deep prefetch ----------------
__global__ __launch_bounds__(256, 4) void agg1_k(
    const fp8_t* __restrict__ xl1, const bf16* __restrict__ xr1,
    const float* __restrict__ par,
    const int* __restrict__ offs, const int* __restrict__ csr,
    bf16* __restrict__ hout) {
  const int dst = blockIdx.x * 4 + (threadIdx.x >> 6);
  if (dst >= N_NODES) return;
  const int lane = threadIdx.x & 63;
  const int g = lane >> 5;        // 2 edge groups
  const int sl = lane & 31;
  const int chb = sl * 8;

  f2 r2[4], a2[4];
  load8bf2(xr1 + (size_t)dst * F1 + chb, r2);
  {
    float4 aa = *(const float4*)(par + P_ATT1 + chb);
    float4 ab = *(const float4*)(par + P_ATT1 + chb + 4);
    a2[0].x = aa.x; a2[0].y = aa.y; a2[1].x = aa.z; a2[1].y = aa.w;
    a2[2].x = ab.x; a2[2].y = ab.y; a2[3].x = ab.z; a2[3].y = ab.w;
  }

  const int e0 = offs[dst], e1 = offs[dst + 1];
  const f2 zf2 = {0.f, 0.f};
  f2 acc2[4];
#pragma unroll
  for (int j = 0; j < 4; j++) acc2[j] = zf2;
  float denom = 0.f;

  const uint2 zq = {0, 0};
  // prime: pair (e0+g, e0+g+2)
  int ea = e0 + g, eb = e0 + g + 2;
  bool va = ea < e1, vb = eb < e1;
  uint2 qa = va ? *(const uint2*)(xl1 + (size_t)csr[ea] * F1 + chb) : zq;
  uint2 qb = vb ? *(const uint2*)(xl1 + (size_t)csr[eb] * F1 + chb) : zq;

  for (int base = e0; base < e1; base += 4) {
    const uint2 qac = qa, qbc = qb;
    const bool vac = va, vbc = vb;
    // prefetch next pair
    int en = base + 4 + g;
    va = en < e1; vb = (en + 2) < e1;
    qa = va ? *(const uint2*)(xl1 + (size_t)csr[en] * F1 + chb) : zq;
    qb = vb ? *(const uint2*)(xl1 + (size_t)csr[en + 2] * F1 + chb) : zq;

    f2 v2a[4], v2b[4];
    unpack8fp8(qac, v2a);
    unpack8fp8(qbc, v2b);
    f2 lta2 = zf2, ltb2 = zf2;
#pragma unroll
    for (int j = 0; j < 4; j++) {
      lta2 = lrelu2(v2a[j] + r2[j]) * a2[j] + lta2;
      ltb2 = lrelu2(v2b[j] + r2[j]) * a2[j] + ltb2;
    }
    float lta = vac ? (lta2.x + lta2.y) : -1e30f;
    float ltb = vbc ? (ltb2.x + ltb2.y) : -1e30f;
    lta += __shfl_xor(lta, 1, 64);  ltb += __shfl_xor(ltb, 1, 64);
    lta += __shfl_xor(lta, 2, 64);  ltb += __shfl_xor(ltb, 2, 64);
    lta += __shfl_xor(lta, 4, 64);  ltb += __shfl_xor(ltb, 4, 64);
    float pa = __expf(fminf(lta, 60.f));
    float pb = __expf(fminf(ltb, 60.f));
    denom += pa + pb;
    f2 pva; pva.x = pa; pva.y = pa;
    f2 pvb; pvb.x = pb; pvb.y = pb;
#pragma unroll
    for (int j = 0; j < 4; j++) {
      acc2[j] = pva * v2a[j] + acc2[j];
      acc2[j] = pvb * v2b[j] + acc2[j];
    }
  }

  denom += __shfl_xor(denom, 32, 64);
#pragma unroll
  for (int j = 0; j < 4; j++) {
    acc2[j].x += __shfl_xor(acc2[j].x, 32, 64);
    acc2[j].y += __shfl_xor(acc2[j].y, 32, 64);
  }

  if (g == 0) {
    float inv = 1.f / (denom + EPS_A);
    __align__(16) bf16 ob[8];
#pragma unroll
    for (int j = 0; j < 4; j++) {
      float o0 = fmaxf(acc2[j].x * inv + par[P_BIAS1 + chb + 2*j],     0.f);
      float o1 = fmaxf(acc2[j].y * inv + par[P_BIAS1 + chb + 2*j + 1], 0.f);
      ob[2*j] = (bf16)o0; ob[2*j+1] = (bf16)o1;
    }
    *(uint4*)(hout + (size_t)dst * F1 + chb) = *(uint4*)ob;
  }
}

// ---------------- layer-2 aggregation: 4 groups x 16 lanes, paired edges ----------------
__global__ __launch_bounds__(256, 4) void agg2_k(
    const fp8_t* __restrict__ xl2, const bf16* __restrict__ xr2,
    const float* __restrict__ par,
    const int* __restrict__ offs, const int* __restrict__ csr,
    bf16* __restrict__ h2) {
  const int dst = blockIdx.x * 4 + (threadIdx.x >> 6);
  if (dst >= N_NODES) return;
  const int lane = threadIdx.x & 63;
  const int g = lane >> 4;        // 4 edge groups
  const int sl = lane & 15;
  const int chb = sl * 8;

  f2 r2[4], a2[4];
  load8bf2(xr2 + (size_t)dst * F2 + chb, r2);
  {
    float4 aa = *(const float4*)(par + P_ATT2 + chb);
    float4 ab = *(const float4*)(par + P_ATT2 + chb + 4);
    a2[0].x = aa.x; a2[0].y = aa.y; a2[1].x = aa.z; a2[1].y = aa.w;
    a2[2].x = ab.x; a2[2].y = ab.y; a2[3].x = ab.z; a2[3].y = ab.w;
  }

  const int e0 = offs[dst], e1 = offs[dst + 1];
  const f2 zf2 = {0.f, 0.f};
  f2 acc2[4];
#pragma unroll
  for (int j = 0; j < 4; j++) acc2[j] = zf2;
  float denom = 0.f;

  const uint2 zq = {0, 0};
  int ea = e0 + g, eb = e0 + g + 4;
  bool va = ea < e1, vb = eb < e1;
  uint2 qa = va ? *(const uint2*)(xl2 + (size_t)csr[ea] * F2 + chb) : zq;
  uint2 qb = vb ? *(const uint2*)(xl2 + (size_t)csr[eb] * F2 + chb) : zq;

  for (int base = e0; base < e1; base += 8) {
    const uint2 qac = qa, qbc = qb;
    const bool vac = va, vbc = vb;
    int en = base + 8 + g;
    va = en < e1; vb = (en + 4) < e1;
    qa = va ? *(const uint2*)(xl2 + (size_t)csr[en] * F2 + chb) : zq;
    qb = vb ? *(const uint2*)(xl2 + (size_t)csr[en + 4] * F2 + chb) : zq;

    f2 v2a[4], v2b[4];
    unpack8fp8(qac, v2a);
    unpack8fp8(qbc, v2b);
    f2 lta2 = zf2, ltb2 = zf2;
#pragma unroll
    for (int j = 0; j < 4; j++) {
      lta2 = lrelu2(v2a[j] + r2[j]) * a2[j] + lta2;
      ltb2 = lrelu2(v2b[j] + r2[j]) * a2[j] + ltb2;
    }
    float lta = vac ? (lta2.x + lta2.y) : -1e30f;
    float ltb = vbc ? (ltb2.x + ltb2.y) : -1e30f;
    lta += __shfl_xor(lta, 1, 64);  ltb += __shfl_xor(ltb, 1, 64);
    lta += __shfl_xor(lta, 2, 64);  ltb += __shfl_xor(ltb, 2, 64);
    lta += __shfl_xor(lta, 4, 64);  ltb += __shfl_xor(ltb, 4, 64);
    lta += __shfl_xor(lta, 8, 64);  ltb += __shfl_xor(ltb, 8, 64);
    float pa = __expf(fminf(lta, 60.f));
    float pb = __expf(fminf(ltb, 60.f));
    denom += pa + pb;
    f2 pva; pva.x = pa; pva.y = pa;
    f2 pvb; pvb.x = pb; pvb.y = pb;
#pragma unroll
    for (int j = 0; j < 4; j++) {
      acc2[j] = pva * v2a[j] + acc2[j];
      acc2[j] = pvb * v2b[j] + acc2[j];
    }
  }

#pragma unroll
  for (int m = 16; m <= 32; m <<= 1) {
    denom += __shfl_xor(denom, m, 64);
#pragma unroll
    for (int j = 0; j < 4; j++) {
      acc2[j].x += __shfl_xor(acc2[j].x, m, 64);
      acc2[j].y += __shfl_xor(acc2[j].y, m, 64);
    }
  }

  if (g == 0) {
    float inv = 1.f / (denom + EPS_A);
    __align__(16) bf16 ob[8];
#pragma unroll
    for (int j = 0; j < 4; j++) {
      float o0 = fmaxf(acc2[j].x * inv + par[P_BIAS2 + chb + 2*j],     0.f);
      float o1 = fmaxf(acc2[j].y * inv + par[P_BIAS2 + chb + 2*j + 1], 0.f);
      ob[2*j] = (bf16)o0; ob[2*j+1] = (bf16)o1;
    }
    *(uint4*)(h2 + (size_t)dst * F2 + chb) = *(uint4*)ob;
  }
}

// ---------------- pooling ----------------
__global__ __launch_bounds__(256) void pool_k(
    const bf16* __restrict__ h2, const int* __restrict__ gs,
    const int* __restrict__ ge, const void* __restrict__ x,
    void* __restrict__ out) {
  const int flag = detect_f32_wave(x);
  const int g = blockIdx.x;
  const int t = threadIdx.x;
  const int c = t & 127, half = t >> 7;
  int s = gs[g], e = ge[g];
  if (s < 0 || e < s) { s = 0; e = -1; }
  float sum = 0.f;
  for (int n = s + half; n <= e; n += 2)
    sum += (float)h2[(size_t)n * F2 + c];
  __shared__ float red[128];
  if (half == 1) red[c] = sum;
  __syncthreads();
  if (half == 0) {
    float tot = sum + red[c];
    float cnt = (e >= s) ? (float)(e - s + 1) : 1.f;
    float v = tot / cnt;
    if (flag) ((float*)out)[g * F2 + c] = v;
    else      ((bf16*)out)[g * F2 + c] = (bf16)v;
  }
}

// ---------------- launch ----------------
extern "C" void kernel_launch(void* const* d_in, const int* in_sizes, int n_in,
                              void* d_out, int out_size, void* d_ws, size_t ws_size,
                              hipStream_t stream) {
  (void)in_sizes; (void)n_in; (void)out_size; (void)ws_size;
  const void* x     = d_in[0];
  const int*  ei    = (const int*)d_in[1];
  const int*  batch = (const int*)d_in[2];

  char* ws = (char*)d_ws;
  float* par  = (float*)(ws + OFF_PAR);
  fp8_t* xl1 = (fp8_t*)(ws + OFF_XL1);
  bf16* xr1 = (bf16*)(ws + OFF_XR1);
  bf16* h   = (bf16*)(ws + OFF_H);
  fp8_t* xl2 = (fp8_t*)(ws + OFF_XL2);
  bf16* xr2 = (bf16*)(ws + OFF_XR2);
  bf16* h2  = (bf16*)(ws + OFF_H2);
  bf16* xb  = (bf16*)(ws + OFF_XB);
  bf16* wt1 = (bf16*)(ws + OFF_WT1);
  bf16* wt2 = (bf16*)(ws + OFF_WT2);
  int* cnt    = (int*)(ws + OFF_CNT);
  int* offs   = (int*)(ws + OFF_OFFS);
  int* csr    = (int*)(ws + OFF_CSR);
  int* gs     = (int*)(ws + OFF_GS);
  int* ge     = (int*)(ws + OFF_GE);
  int* bsum   = (int*)(ws + OFF_BS);
  int* rank   = (int*)(ws + OFF_RANK);

  hipMemsetAsync(cnt, 0, (size_t)N_NODES * 4, stream);
  hipMemsetAsync(gs, 0xFF, (size_t)(OFF_WT1 - OFF_GS), stream);  // gs/ge = -1

  PrepArgs pa;
  pa.x = x; pa.ei = ei; pa.batch = batch;
  for (int i = 0; i < 12; i++) pa.src[i] = d_in[3 + i];
  const int prep_blocks = B_CVT + B_XP + B_W1 + B_W2 + B_BND + B_CNT;
  prep_k<<<prep_blocks, 256, 0, stream>>>(pa, par, xb, wt1, wt2, gs, ge, cnt, rank);

  scan_a<<<SCAN_BLKS, 1024, 0, stream>>>(cnt, offs, bsum);
  scan_c<<<(N_NODES + 255) / 256, 256, 0, stream>>>(bsum, offs);

  gemm1_scatter_k<<<GBLK + SBL, 256, 0, stream>>>(xb, wt1, par, xl1, xr1,
                                                  ei, offs, rank, csr);
  agg1_k<<<(N_NODES + 3) / 4, 256, 0, stream>>>(xl1, xr1, par, offs, csr, h);
  gemm2_mfma_k<<<GBLK, 256, 0, stream>>>(h, wt2, par, xl2, xr2);
  agg2_k<<<(N_NODES + 3) / 4, 256, 0, stream>>>(xl2, xr2, par, offs, csr, h2);
  pool_k<<<NGRAPH, 256, 0, stream>>>(h2, gs, ge, x, d_out);
}

// Round 16
// 322.367 us; speedup vs baseline: 1.2607x; 1.1843x over previous
//
#include <hip/hip_runtime.h>
#include <hip/hip_bf16.h>
#include <limits.h>

// ---------------- problem constants ----------------
#define N_NODES 50000
#define N_EDGES 800000
#define TOT_E   (N_EDGES + N_NODES)   // with self loops
#define IN_F    38
#define HIDC    64
#define NH      4
#define F1      256                    // NH*HIDC
#define F2      128                    // OUT
#define NGRAPH  128
#define NEG_SLOPE 0.2f
#define EPS_A   1e-16f

typedef __hip_bfloat16 bf16;
typedef unsigned char fp8_t;           // OCP e4m3 raw byte
typedef __attribute__((ext_vector_type(8))) short short8;
typedef __attribute__((ext_vector_type(16))) float f32x16;
typedef __attribute__((ext_vector_type(2))) float f2;   // lowers to VOP3P v_pk_*_f32

// ---------------- ws layout ----------------
constexpr size_t al256(size_t x) { return (x + 255) & ~(size_t)255; }

// converted-params element offsets (f32 elements)
#define P_WL1   0
#define P_BL1   (P_WL1 + IN_F * F1)
#define P_WR1   (P_BL1 + F1)
#define P_BR1   (P_WR1 + IN_F * F1)
#define P_ATT1  (P_BR1 + F1)
#define P_BIAS1 (P_ATT1 + F1)
#define P_WL2   (P_BIAS1 + F1)
#define P_BL2   (P_WL2 + F1 * F2)
#define P_WR2   (P_BL2 + F2)
#define P_BR2   (P_WR2 + F1 * F2)
#define P_ATT2  (P_BR2 + F2)
#define P_BIAS2 (P_ATT2 + F2)
#define P_TOTAL (P_BIAS2 + F2)         // 86528 = 338*256

constexpr size_t OFF_PAR  = 256;
constexpr size_t OFF_XL1  = OFF_PAR + al256((size_t)P_TOTAL * 4);   // fp8 N*256; reused as h2
constexpr size_t OFF_XR1  = OFF_XL1 + al256((size_t)N_NODES * F1 * 2);
constexpr size_t OFF_H    = OFF_XR1 + al256((size_t)N_NODES * F1 * 2);
constexpr size_t OFF_XL2  = OFF_H   + al256((size_t)N_NODES * F1 * 2);  // fp8 N*128
constexpr size_t OFF_XR2  = OFF_XL2 + al256((size_t)N_NODES * F2 * 2);
constexpr size_t OFF_CNT  = OFF_XR2 + al256((size_t)N_NODES * F2 * 2);
constexpr size_t OFF_OFFS = OFF_CNT + al256((size_t)N_NODES * 4);
constexpr size_t OFF_CSR  = OFF_OFFS+ al256((size_t)(N_NODES + 1) * 4);
constexpr size_t OFF_GS   = OFF_CSR + al256((size_t)TOT_E * 4);
constexpr size_t OFF_GE   = OFF_GS  + al256((size_t)NGRAPH * 4);
constexpr size_t OFF_WT1  = OFF_GE  + al256((size_t)NGRAPH * 4);    // 512x64 bf16
constexpr size_t OFF_WT2  = OFF_WT1 + al256((size_t)512 * 64 * 2);  // 256x256 bf16
constexpr size_t OFF_BS   = OFF_WT2 + al256((size_t)256 * 256 * 2); // 49 block sums
constexpr size_t OFF_PSUM = OFF_BS  + al256(64 * 4);                // 128x128 f32 pool partials
constexpr size_t OFF_RANK = OFF_PSUM+ al256((size_t)NGRAPH * F2 * 4); // per-edge rank
constexpr size_t OFF_H2   = OFF_XL1;  // xl1 dead after agg1
constexpr size_t OFF_XB   = OFF_H;    // xb dead before agg1 writes h

#define SCAN_BLKS 49   // ceil(50000/1024)
#define GBLK 1563      // ceil(50000/32)
#define SBL  831       // ceil(TOT_E/1024)

// ---------------- helpers ----------------
__device__ __forceinline__ void unpack8bf2(uint4 q, f2* f) {
  unsigned v[4] = {q.x, q.y, q.z, q.w};
#pragma unroll
  for (int i = 0; i < 4; i++) {
    f2 t;
    t.x = __uint_as_float(v[i] << 16);
    t.y = __uint_as_float(v[i] & 0xffff0000u);
    f[i] = t;
  }
}

__device__ __forceinline__ void load8bf2(const bf16* __restrict__ p, f2* f) {
  unpack8bf2(*(const uint4*)p, f);
}

// 8 fp8 bytes -> 4 x f2 via HW v_cvt_pk_f32_fp8
__device__ __forceinline__ void unpack8fp8(uint2 q, f2* f) {
  f[0] = __builtin_amdgcn_cvt_pk_f32_fp8(q.x, false);
  f[1] = __builtin_amdgcn_cvt_pk_f32_fp8(q.x, true);
  f[2] = __builtin_amdgcn_cvt_pk_f32_fp8(q.y, false);
  f[3] = __builtin_amdgcn_cvt_pk_f32_fp8(q.y, true);
}

__device__ __forceinline__ fp8_t f32_to_fp8(float v) {
  return (fp8_t)(__builtin_amdgcn_cvt_pk_fp8_f32(v, v, 0, false) & 0xFF);
}

// leaky_relu(s) = 0.6*s + 0.4*|s|
__device__ __forceinline__ f2 lrelu2(f2 s) {
  f2 as;
  as.x = __uint_as_float(__float_as_uint(s.x) & 0x7fffffffu);
  as.y = __uint_as_float(__float_as_uint(s.y) & 0x7fffffffu);
  return 0.6f * s + 0.4f * as;
}

// wave-cooperative dtype sniff: 1 = inputs are f32, 0 = bf16.
__device__ __forceinline__ int detect_f32_wave(const void* __restrict__ x) {
  const unsigned short* u = (const unsigned short*)x;
  unsigned short b = u[threadIdx.x & 63];
  int e = (b >> 7) & 0xFF;
  unsigned long long m = __ballot(!((e == 0) || (e >= 96 && e <= 158)));
  return __popcll(m) > 8;
}

// ---------------- fused prep kernel (MLP-widened, R15) ----------------
#define B_CVT  338
#define B_XP   1563    // 8 channels/thread
#define B_W1   128
#define B_W2   256
#define B_BND  196
#define B_CNT  831     // 4 edges/thread

struct PrepArgs {
  const void* x;
  const void* src[12];
  const int* ei;
  const int* batch;
};

__global__ __launch_bounds__(256) void prep_k(
    PrepArgs a, float* __restrict__ par, bf16* __restrict__ xb,
    bf16* __restrict__ wt1, bf16* __restrict__ wt2,
    int* __restrict__ gs, int* __restrict__ ge, int* __restrict__ cnt,
    int* __restrict__ rank) {
  int b = blockIdx.x;
  const int tid = threadIdx.x;

  if (b < B_CVT) {                       // ---- param convert -> f32 ----
    const int flag = detect_f32_wave(a.x);
    int idx = b * 256 + tid;
    const void* p; int base;
    if      (idx < P_BL1)  { p = a.src[0];  base = P_WL1; }
    else if (idx < P_WR1)  { p = a.src[1];  base = P_BL1; }
    else if (idx < P_BR1)  { p = a.src[2];  base = P_WR1; }
    else if (idx < P_ATT1) { p = a.src[3];  base = P_BR1; }
    else if (idx < P_BIAS1){ p = a.src[4];  base = P_ATT1; }
    else if (idx < P_WL2)  { p = a.src[5];  base = P_BIAS1; }
    else if (idx < P_BL2)  { p = a.src[6];  base = P_WL2; }
    else if (idx < P_WR2)  { p = a.src[7];  base = P_BL2; }
    else if (idx < P_BR2)  { p = a.src[8];  base = P_WR2; }
    else if (idx < P_ATT2) { p = a.src[9];  base = P_BR2; }
    else if (idx < P_BIAS2){ p = a.src[10]; base = P_ATT2; }
    else                   { p = a.src[11]; base = P_BIAS2; }
    int li = idx - base;
    par[idx] = flag ? ((const float*)p)[li] : (float)((const bf16*)p)[li];
    return;
  }
  b -= B_CVT;
  if (b < B_XP) {                        // ---- x -> xb, 8 ch/thread ----
    const int flag = detect_f32_wave(a.x);
    int gid = b * 256 + tid;
    int n = gid >> 3, k0 = (gid & 7) * 8;
    float v[8];
#pragma unroll
    for (int j = 0; j < 8; j++) {
      int k = k0 + j;
      v[j] = 0.f;
      if (k < IN_F) {
        int idx = n * IN_F + k;
        v[j] = flag ? ((const float*)a.x)[idx] : (float)((const bf16*)a.x)[idx];
      }
    }
    __align__(16) bf16 ob[8];
#pragma unroll
    for (int j = 0; j < 8; j++) ob[j] = (bf16)v[j];
    *(uint4*)(xb + (size_t)n * 64 + k0) = *(uint4*)ob;
    return;
  }
  b -= B_XP;
  if (b < B_W1) {                        // ---- Wt1[n][k] 512x64 ----
    const int flag = detect_f32_wave(a.x);
    int i = b * 256 + tid;
    int n = i >> 6, k = i & 63;
    float v = 0.f;
    if (k < IN_F) {
      const void* W = (n < F1) ? a.src[0] : a.src[2];
      int col = (n < F1) ? n : n - F1;
      int idx = k * F1 + col;
      v = flag ? ((const float*)W)[idx] : (float)((const bf16*)W)[idx];
    }
    wt1[i] = (bf16)v;
    return;
  }
  b -= B_W1;
  if (b < B_W2) {                        // ---- Wt2[n][k] 256x256 ----
    const int flag = detect_f32_wave(a.x);
    int i = b * 256 + tid;
    int n = i >> 8, k = i & 255;
    const void* W = (n < F2) ? a.src[6] : a.src[8];
    int col = (n < F2) ? n : n - F2;
    int idx = k * F2 + col;
    float v = flag ? ((const float*)W)[idx] : (float)((const bf16*)W)[idx];
    wt2[i] = (bf16)v;
    return;
  }
  b -= B_W2;
  if (b < B_BND) {                       // ---- graph bounds (batch sorted) ----
    int n = b * 256 + tid;
    if (n >= N_NODES) return;
    int bb = a.batch[n];
    if (n == 0) gs[bb] = 0;
    else {
      int bp = a.batch[n - 1];
      if (bp != bb) { gs[bb] = n; ge[bp] = n - 1; }
    }
    if (n == N_NODES - 1) ge[bb] = N_NODES - 1;
    return;
  }
  b -= B_BND;
  {                                      // ---- degree count + rank, 4 edges/thread ----
    int base = b * 1024 + tid;
    int dstv[4]; bool val[4];
#pragma unroll
    for (int i = 0; i < 4; i++) {
      int e = base + i * 256;
      val[i] = e < TOT_E;
      dstv[i] = 0;
      if (val[i])
        dstv[i] = (e < N_EDGES) ? a.ei[N_EDGES + e] : (e - N_EDGES);
    }
#pragma unroll
    for (int i = 0; i < 4; i++) {
      int e = base + i * 256;
      if (val[i]) rank[e] = atomicAdd(&cnt[dstv[i]], 1);
    }
  }
}

// ---------------- fused: GEMM1 (MFMA 32x32x16) || atomic-free scatter ----------------
__global__ __launch_bounds__(256) void gemm1_scatter_k(
    const bf16* __restrict__ xb, const bf16* __restrict__ wt1,
    const float* __restrict__ par,
    fp8_t* __restrict__ xl1, bf16* __restrict__ xr1,
    const int* __restrict__ ei, const int* __restrict__ offs,
    const int* __restrict__ rank, int* __restrict__ csr) {
  if (blockIdx.x >= GBLK) {              // ---- scatter path ----
    int base = (blockIdx.x - GBLK) * 1024 + threadIdx.x;
#pragma unroll
    for (int i = 0; i < 4; i++) {
      int e = base + i * 256;
      if (e >= TOT_E) continue;
      int src, dst;
      if (e < N_EDGES) { src = ei[e]; dst = ei[N_EDGES + e]; }
      else             { src = dst = e - N_EDGES; }
      csr[offs[dst] + rank[e]] = src;
    }
    return;
  }
  // ---- gemm1 path ----
  const int w = threadIdx.x >> 6, lane = threadIdx.x & 63;
  const int m0 = blockIdx.x * 32;
  const int colbase = w * 128;
  const int lm = lane & 31;
  const int kh = lane >> 5;

  int arow = m0 + lm; if (arow >= N_NODES) arow = N_NODES - 1;
  short8 afr[4];
#pragma unroll
  for (int kk = 0; kk < 4; kk++)
    afr[kk] = *(const short8*)(xb + (size_t)arow * 64 + kk * 16 + kh * 8);

  f32x16 acc[4] = {};
#pragma unroll
  for (int t = 0; t < 4; t++) {
    int n = colbase + t * 32 + lm;
#pragma unroll
    for (int kk = 0; kk < 4; kk++) {
      short8 b = *(const short8*)(wt1 + (size_t)n * 64 + kk * 16 + kh * 8);
      acc[t] = __builtin_amdgcn_mfma_f32_32x32x16_bf16(afr[kk], b, acc[t], 0, 0, 0);
    }
  }

#pragma unroll
  for (int t = 0; t < 4; t++) {
    int col = colbase + t * 32 + lm;
    if (col < F1) {
      float bv = par[P_BL1 + col];
#pragma unroll
      for (int reg = 0; reg < 16; reg++) {
        int row = m0 + (reg & 3) + 8 * (reg >> 2) + 4 * kh;
        if (row < N_NODES)
          xl1[(size_t)row * F1 + col] = f32_to_fp8(acc[t][reg] + bv);
      }
    } else {
      int c = col - F1;
      float bv = par[P_BR1 + c];
#pragma unroll
      for (int reg = 0; reg < 16; reg++) {
        int row = m0 + (reg & 3) + 8 * (reg >> 2) + 4 * kh;
        if (row < N_NODES)
          xr1[(size_t)row * F1 + c] = (bf16)(acc[t][reg] + bv);
      }
    }
  }
}

// ---------------- GEMM 2 (MFMA 32x32x16) ----------------
__global__ __launch_bounds__(256) void gemm2_mfma_k(
    const bf16* __restrict__ h, const bf16* __restrict__ wt2,
    const float* __restrict__ par,
    fp8_t* __restrict__ xl2, bf16* __restrict__ xr2) {
  const int w = threadIdx.x >> 6, lane = threadIdx.x & 63;
  const int m0 = blockIdx.x * 32;
  const int colbase = w * 64;
  const int lm = lane & 31;
  const int kh = lane >> 5;

  int arow = m0 + lm; if (arow >= N_NODES) arow = N_NODES - 1;
  const bf16* hrow = h + (size_t)arow * F1 + kh * 8;

  f32x16 acc[2] = {};
#pragma unroll
  for (int kk = 0; kk < 16; kk++) {
    short8 a = *(const short8*)(hrow + kk * 16);
#pragma unroll
    for (int t = 0; t < 2; t++) {
      int n = colbase + t * 32 + lm;
      short8 b = *(const short8*)(wt2 + (size_t)n * 256 + kk * 16 + kh * 8);
      acc[t] = __builtin_amdgcn_mfma_f32_32x32x16_bf16(a, b, acc[t], 0, 0, 0);
    }
  }

#pragma unroll
  for (int t = 0; t < 2; t++) {
    int col = colbase + t * 32 + lm;
    if (col < F2) {
      float bv = par[P_BL2 + col];
#pragma unroll
      for (int reg = 0; reg < 16; reg++) {
        int row = m0 + (reg & 3) + 8 * (reg >> 2) + 4 * kh;
        if (row < N_NODES)
          xl2[(size_t)row * F2 + col] = f32_to_fp8(acc[t][reg] + bv);
      }
    } else {
      int c = col - F2;
      float bv = par[P_BR2 + c];
#pragma unroll
      for (int reg = 0; reg < 16; reg++) {
        int row = m0 + (reg & 3) + 8 * (reg >> 2) + 4 * kh;
        if (row < N_NODES)
          xr2[(size_t)row * F2 + c] = (bf16)(acc[t][reg] + bv);
      }
    }
  }
}

// ---------------- CSR scan (2-phase) ----------------
__global__ __launch_bounds__(1024) void scan_a(const int* __restrict__ cnt,
                                               int* __restrict__ offs,
                                               int* __restrict__ bsum) {
  __shared__ int wsum[16];
  const int t = threadIdx.x;
  const int lane = t & 63, w = t >> 6;
  int idx = blockIdx.x * 1024 + t;
  int v = (idx < N_NODES) ? cnt[idx] : 0;
  int s = v;
#pragma unroll
  for (int off = 1; off < 64; off <<= 1) {
    int u = __shfl_up(s, off, 64);
    if (lane >= off) s += u;
  }
  if (lane == 63) wsum[w] = s;
  __syncthreads();
  int prefix = 0;
  for (int i = 0; i < w; i++) prefix += wsum[i];
  if (idx < N_NODES) offs[idx] = prefix + s - v;
  if (t == 1023) bsum[blockIdx.x] = prefix + s;
}

__global__ void scan_c(const int* __restrict__ bsum, int* __restrict__ offs) {
  const int t = threadIdx.x;
  const int grp = blockIdx.x >> 2;
  __shared__ int sboff;
  if (t < 64) {
    int v = (t < SCAN_BLKS) ? bsum[t] : 0;
    int s = v;
#pragma unroll
    for (int off = 1; off < 64; off <<= 1) {
      int u = __shfl_up(s, off, 64);
      if (t >= off) s += u;
    }
    if (t == grp) sboff = s - v;
  }
  __syncthreads();
  int idx = blockIdx.x * 256 + t;
  if (idx < N_NODES) offs[idx] += sboff;
  if (blockIdx.x == 0 && t == 0) offs[N_NODES] = TOT_E;
}

// ---------------- layer-1 aggregation (R14-winning shape): one wave per dst,
// 2 groups x 32 lanes, fp8 gather 8B/lane, 1-deep register prefetch ----------------
__global__ __launch_bounds__(256, 4) void agg1_k(
    const fp8_t* __restrict__ xl1, const bf16* __restrict__ xr1,
    const float* __restrict__ par,
    const int* __restrict__ offs, const int* __restrict__ csr,
    bf16* __restrict__ hout) {
  const int dst = blockIdx.x * 4 + (threadIdx.x >> 6);
  if (dst >= N_NODES) return;
  const int lane = threadIdx.x & 63;
  const int g = lane >> 5;        // 2 edge groups
  const int sl = lane & 31;
  const int chb = sl * 8;

  f2 r2[4], a2[4];
  load8bf2(xr1 + (size_t)dst * F1 + chb, r2);
  {
    float4 aa = *(const float4*)(par + P_ATT1 + chb);
    float4 ab = *(const float4*)(par + P_ATT1 + chb + 4);
    a2[0].x = aa.x; a2[0].y = aa.y; a2[1].x = aa.z; a2[1].y = aa.w;
    a2[2].x = ab.x; a2[2].y = ab.y; a2[3].x = ab.z; a2[3].y = ab.w;
  }

  const int e0 = offs[dst], e1 = offs[dst + 1];
  const f2 zf2 = {0.f, 0.f};
  f2 acc2[4];
#pragma unroll
  for (int j = 0; j < 4; j++) acc2[j] = zf2;
  float denom = 0.f;

  const uint2 zq = {0, 0};
  int e = e0 + g;
  bool valid = e < e1;
  uint2 q = valid ? *(const uint2*)(xl1 + (size_t)csr[e] * F1 + chb) : zq;

  for (int base = e0; base < e1; base += 2) {
    const uint2 qc = q;
    const bool vc = valid;
    e += 2;
    valid = e < e1;
    q = valid ? *(const uint2*)(xl1 + (size_t)csr[e] * F1 + chb) : zq;

    f2 v2[4];
    unpack8fp8(qc, v2);
    f2 lt2 = zf2;
#pragma unroll
    for (int j = 0; j < 4; j++)
      lt2 = lrelu2(v2[j] + r2[j]) * a2[j] + lt2;
    float lt = vc ? (lt2.x + lt2.y) : -1e30f;
    lt += __shfl_xor(lt, 1, 64);
    lt += __shfl_xor(lt, 2, 64);
    lt += __shfl_xor(lt, 4, 64);
    float p = __expf(fminf(lt, 60.f));
    denom += p;
    f2 pv; pv.x = p; pv.y = p;
#pragma unroll
    for (int j = 0; j < 4; j++) acc2[j] = pv * v2[j] + acc2[j];
  }

  denom += __shfl_xor(denom, 32, 64);
#pragma unroll
  for (int j = 0; j < 4; j++) {
    acc2[j].x += __shfl_xor(acc2[j].x, 32, 64);
    acc2[j].y += __shfl_xor(acc2[j].y, 32, 64);
  }

  if (g == 0) {
    float inv = 1.f / (denom + EPS_A);
    __align__(16) bf16 ob[8];
#pragma unroll
    for (int j = 0; j < 4; j++) {
      float o0 = fmaxf(acc2[j].x * inv + par[P_BIAS1 + chb + 2*j],     0.f);
      float o1 = fmaxf(acc2[j].y * inv + par[P_BIAS1 + chb + 2*j + 1], 0.f);
      ob[2*j] = (bf16)o0; ob[2*j+1] = (bf16)o1;
    }
    *(uint4*)(hout + (size_t)dst * F1 + chb) = *(uint4*)ob;
  }
}

// ---------------- layer-2 aggregation (R14-winning shape): 4 groups x 16 lanes,
// fp8 gather 8B/lane, 1-deep prefetch ----------------
__global__ __launch_bounds__(256, 4) void agg2_k(
    const fp8_t* __restrict__ xl2, const bf16* __restrict__ xr2,
    const float* __restrict__ par,
    const int* __restrict__ offs, const int* __restrict__ csr,
    bf16* __restrict__ h2) {
  const int dst = blockIdx.x * 4 + (threadIdx.x >> 6);
  if (dst >= N_NODES) return;
  const int lane = threadIdx.x & 63;
  const int g = lane >> 4;        // 4 edge groups
  const int sl = lane & 15;
  const int chb = sl * 8;

  f2 r2[4], a2[4];
  load8bf2(xr2 + (size_t)dst * F2 + chb, r2);
  {
    float4 aa = *(const float4*)(par + P_ATT2 + chb);
    float4 ab = *(const float4*)(par + P_ATT2 + chb + 4);
    a2[0].x = aa.x; a2[0].y = aa.y; a2[1].x = aa.z; a2[1].y = aa.w;
    a2[2].x = ab.x; a2[2].y = ab.y; a2[3].x = ab.z; a2[3].y = ab.w;
  }

  const int e0 = offs[dst], e1 = offs[dst + 1];
  const f2 zf2 = {0.f, 0.f};
  f2 acc2[4];
#pragma unroll
  for (int j = 0; j < 4; j++) acc2[j] = zf2;
  float denom = 0.f;

  const uint2 zq = {0, 0};
  int e = e0 + g;
  bool valid = e < e1;
  uint2 q = valid ? *(const uint2*)(xl2 + (size_t)csr[e] * F2 + chb) : zq;

  for (int base = e0; base < e1; base += 4) {
    const uint2 qc = q;
    const bool vc = valid;
    e += 4;
    valid = e < e1;
    q = valid ? *(const uint2*)(xl2 + (size_t)csr[e] * F2 + chb) : zq;

    f2 v2[4];
    unpack8fp8(qc, v2);
    f2 lt2 = zf2;
#pragma unroll
    for (int j = 0; j < 4; j++)
      lt2 = lrelu2(v2[j] + r2[j]) * a2[j] + lt2;
    float lt = vc ? (lt2.x + lt2.y) : -1e30f;
    lt += __shfl_xor(lt, 1, 64);
    lt += __shfl_xor(lt, 2, 64);
    lt += __shfl_xor(lt, 4, 64);
    lt += __shfl_xor(lt, 8, 64);
    float p = __expf(fminf(lt, 60.f));
    denom += p;
    f2 pv; pv.x = p; pv.y = p;
#pragma unroll
    for (int j = 0; j < 4; j++) acc2[j] = pv * v2[j] + acc2[j];
  }

#pragma unroll
  for (int m = 16; m <= 32; m <<= 1) {
    denom += __shfl_xor(denom, m, 64);
#pragma unroll
    for (int j = 0; j < 4; j++) {
      acc2[j].x += __shfl_xor(acc2[j].x, m, 64);
      acc2[j].y += __shfl_xor(acc2[j].y, m, 64);
    }
  }

  if (g == 0) {
    float inv = 1.f / (denom + EPS_A);
    __align__(16) bf16 ob[8];
#pragma unroll
    for (int j = 0; j < 4; j++) {
      float o0 = fmaxf(acc2[j].x * inv + par[P_BIAS2 + chb + 2*j],     0.f);
      float o1 = fmaxf(acc2[j].y * inv + par[P_BIAS2 + chb + 2*j + 1], 0.f);
      ob[2*j] = (bf16)o0; ob[2*j+1] = (bf16)o1;
    }
    *(uint4*)(h2 + (size_t)dst * F2 + chb) = *(uint4*)ob;
  }
}

// ---------------- pooling: 8 slices/graph (1024 blocks) + finalize ----------------
__global__ __launch_bounds__(256) void poolp_k(
    const bf16* __restrict__ h2, const int* __restrict__ gs,
    const int* __restrict__ ge, float* __restrict__ psum) {
  const int g = blockIdx.x >> 3, slice = blockIdx.x & 7;
  const int t = threadIdx.x;
  const int c = t & 127, half = t >> 7;
  int s = gs[g], e = ge[g];
  if (s < 0 || e < s) return;
  float sum = 0.f;
  for (int n = s + slice * 2 + half; n <= e; n += 16)
    sum += (float)h2[(size_t)n * F2 + c];
  atomicAdd(&psum[g * F2 + c], sum);
}

__global__ void poolf_k(const float* __restrict__ psum,
                        const int* __restrict__ gs, const int* __restrict__ ge,
                        const void* __restrict__ x, void* __restrict__ out) {
  int i = blockIdx.x * 256 + threadIdx.x;
  if (i >= NGRAPH * F2) return;
  const int flag = detect_f32_wave(x);
  int g = i >> 7;
  int s = gs[g], e = ge[g];
  float cnt = (s >= 0 && e >= s) ? (float)(e - s + 1) : 1.f;
  float v = psum[i] / cnt;
  if (flag) ((float*)out)[i] = v;
  else      ((bf16*)out)[i] = (bf16)v;
}

// ---------------- launch ----------------
extern "C" void kernel_launch(void* const* d_in, const int* in_sizes, int n_in,
                              void* d_out, int out_size, void* d_ws, size_t ws_size,
                              hipStream_t stream) {
  (void)in_sizes; (void)n_in; (void)out_size; (void)ws_size;
  const void* x     = d_in[0];
  const int*  ei    = (const int*)d_in[1];
  const int*  batch = (const int*)d_in[2];

  char* ws = (char*)d_ws;
  float* par  = (float*)(ws + OFF_PAR);
  fp8_t* xl1 = (fp8_t*)(ws + OFF_XL1);
  bf16* xr1 = (bf16*)(ws + OFF_XR1);
  bf16* h   = (bf16*)(ws + OFF_H);
  fp8_t* xl2 = (fp8_t*)(ws + OFF_XL2);
  bf16* xr2 = (bf16*)(ws + OFF_XR2);
  bf16* h2  = (bf16*)(ws + OFF_H2);
  bf16* xb  = (bf16*)(ws + OFF_XB);
  bf16* wt1 = (bf16*)(ws + OFF_WT1);
  bf16* wt2 = (bf16*)(ws + OFF_WT2);
  int* cnt    = (int*)(ws + OFF_CNT);
  int* offs   = (int*)(ws + OFF_OFFS);
  int* csr    = (int*)(ws + OFF_CSR);
  int* gs     = (int*)(ws + OFF_GS);
  int* ge     = (int*)(ws + OFF_GE);
  int* bsum   = (int*)(ws + OFF_BS);
  float* psum = (float*)(ws + OFF_PSUM);
  int* rank   = (int*)(ws + OFF_RANK);

  hipMemsetAsync(cnt, 0, (size_t)N_NODES * 4, stream);
  hipMemsetAsync(gs, 0xFF, (size_t)(OFF_WT1 - OFF_GS), stream);  // gs/ge = -1
  hipMemsetAsync(psum, 0, (size_t)NGRAPH * F2 * 4, stream);

  PrepArgs pa;
  pa.x = x; pa.ei = ei; pa.batch = batch;
  for (int i = 0; i < 12; i++) pa.src[i] = d_in[3 + i];
  const int prep_blocks = B_CVT + B_XP + B_W1 + B_W2 + B_BND + B_CNT;
  prep_k<<<prep_blocks, 256, 0, stream>>>(pa, par, xb, wt1, wt2, gs, ge, cnt, rank);

  scan_a<<<SCAN_BLKS, 1024, 0, stream>>>(cnt, offs, bsum);
  scan_c<<<(N_NODES + 255) / 256, 256, 0, stream>>>(bsum, offs);

  gemm1_scatter_k<<<GBLK + SBL, 256, 0, stream>>>(xb, wt1, par, xl1, xr1,
                                                  ei, offs, rank, csr);
  agg1_k<<<(N_NODES + 3) / 4, 256, 0, stream>>>(xl1, xr1, par, offs, csr, h);
  gemm2_mfma_k<<<GBLK, 256, 0, stream>>>(h, wt2, par, xl2, xr2);
  agg2_k<<<(N_NODES + 3) / 4, 256, 0, stream>>>(xl2, xr2, par, offs, csr, h2);
  poolp_k<<<NGRAPH * 8, 256, 0, stream>>>(h2, gs, ge, psum);
  poolf_k<<<(NGRAPH * F2 + 255) / 256, 256, 0, stream>>>(psum, gs, ge, x, d_out);
}

// Round 17
// 318.388 us; speedup vs baseline: 1.2765x; 1.0125x over previous
//
#include <hip/hip_runtime.h>
#include <hip/hip_bf16.h>
#include <limits.h>

// ---------------- problem constants ----------------
#define N_NODES 50000
#define N_EDGES 800000
#define TOT_E   (N_EDGES + N_NODES)   // with self loops
#define IN_F    38
#define HIDC    64
#define NH      4
#define F1      256                    // NH*HIDC
#define F2      128                    // OUT
#define NGRAPH  128
#define NEG_SLOPE 0.2f
#define EPS_A   1e-16f

typedef __hip_bfloat16 bf16;
typedef unsigned char fp8_t;           // OCP e4m3 raw byte
typedef __attribute__((ext_vector_type(8))) short short8;
typedef __attribute__((ext_vector_type(16))) float f32x16;
typedef __attribute__((ext_vector_type(2))) float f2;   // lowers to VOP3P v_pk_*_f32

// ---------------- ws layout ----------------
constexpr size_t al256(size_t x) { return (x + 255) & ~(size_t)255; }

// converted-params element offsets (f32 elements)
#define P_WL1   0
#define P_BL1   (P_WL1 + IN_F * F1)
#define P_WR1   (P_BL1 + F1)
#define P_BR1   (P_WR1 + IN_F * F1)
#define P_ATT1  (P_BR1 + F1)
#define P_BIAS1 (P_ATT1 + F1)
#define P_WL2   (P_BIAS1 + F1)
#define P_BL2   (P_WL2 + F1 * F2)
#define P_WR2   (P_BL2 + F2)
#define P_BR2   (P_WR2 + F1 * F2)
#define P_ATT2  (P_BR2 + F2)
#define P_BIAS2 (P_ATT2 + F2)
#define P_TOTAL (P_BIAS2 + F2)         // 86528 = 338*256

constexpr size_t OFF_PAR  = 256;
constexpr size_t OFF_XL1  = OFF_PAR + al256((size_t)P_TOTAL * 4);   // fp8 N*256; reused as h2
constexpr size_t OFF_XR1  = OFF_XL1 + al256((size_t)N_NODES * F1 * 2);
constexpr size_t OFF_H    = OFF_XR1 + al256((size_t)N_NODES * F1 * 2);
constexpr size_t OFF_XL2  = OFF_H   + al256((size_t)N_NODES * F1 * 2);  // fp8 N*128
constexpr size_t OFF_XR2  = OFF_XL2 + al256((size_t)N_NODES * F2 * 2);
// --- zero-init region (single memset): cnt | gs | ge | psum ---
constexpr size_t OFF_CNT  = OFF_XR2 + al256((size_t)N_NODES * F2 * 2);
constexpr size_t OFF_GS   = OFF_CNT + al256((size_t)N_NODES * 4);
constexpr size_t OFF_GE   = OFF_GS  + al256((size_t)NGRAPH * 4);
constexpr size_t OFF_PSUM = OFF_GE  + al256((size_t)NGRAPH * 4);
constexpr size_t OFF_ZEND = OFF_PSUM+ al256((size_t)NGRAPH * F2 * 4);
// --- rest ---
constexpr size_t OFF_OFFS = OFF_ZEND;
constexpr size_t OFF_CSR  = OFF_OFFS+ al256((size_t)(N_NODES + 1) * 4);
constexpr size_t OFF_WT1  = OFF_CSR + al256((size_t)TOT_E * 4);     // 512x64 bf16
constexpr size_t OFF_WT2  = OFF_WT1 + al256((size_t)512 * 64 * 2);  // 256x256 bf16
constexpr size_t OFF_BS   = OFF_WT2 + al256((size_t)256 * 256 * 2); // 49 block sums
constexpr size_t OFF_RANK = OFF_BS  + al256(64 * 4);                // per-edge rank
constexpr size_t OFF_H2   = OFF_XL1;  // xl1 dead after agg1
constexpr size_t OFF_XB   = OFF_H;    // xb dead before agg1 writes h

#define SCAN_BLKS 49   // ceil(50000/1024)
#define GBLK 1563      // ceil(50000/32)
#define SBL  831       // ceil(TOT_E/1024)

// ---------------- helpers ----------------
__device__ __forceinline__ void unpack8bf2(uint4 q, f2* f) {
  unsigned v[4] = {q.x, q.y, q.z, q.w};
#pragma unroll
  for (int i = 0; i < 4; i++) {
    f2 t;
    t.x = __uint_as_float(v[i] << 16);
    t.y = __uint_as_float(v[i] & 0xffff0000u);
    f[i] = t;
  }
}

__device__ __forceinline__ void load8bf2(const bf16* __restrict__ p, f2* f) {
  unpack8bf2(*(const uint4*)p, f);
}

// 8 fp8 bytes -> 4 x f2 via HW v_cvt_pk_f32_fp8
__device__ __forceinline__ void unpack8fp8(uint2 q, f2* f) {
  f[0] = __builtin_amdgcn_cvt_pk_f32_fp8(q.x, false);
  f[1] = __builtin_amdgcn_cvt_pk_f32_fp8(q.x, true);
  f[2] = __builtin_amdgcn_cvt_pk_f32_fp8(q.y, false);
  f[3] = __builtin_amdgcn_cvt_pk_f32_fp8(q.y, true);
}

__device__ __forceinline__ fp8_t f32_to_fp8(float v) {
  return (fp8_t)(__builtin_amdgcn_cvt_pk_fp8_f32(v, v, 0, false) & 0xFF);
}

// leaky_relu(s) = 0.6*s + 0.4*|s|
__device__ __forceinline__ f2 lrelu2(f2 s) {
  f2 as;
  as.x = __uint_as_float(__float_as_uint(s.x) & 0x7fffffffu);
  as.y = __uint_as_float(__float_as_uint(s.y) & 0x7fffffffu);
  return 0.6f * s + 0.4f * as;
}

// wave-cooperative dtype sniff: 1 = inputs are f32, 0 = bf16.
__device__ __forceinline__ int detect_f32_wave(const void* __restrict__ x) {
  const unsigned short* u = (const unsigned short*)x;
  unsigned short b = u[threadIdx.x & 63];
  int e = (b >> 7) & 0xFF;
  unsigned long long m = __ballot(!((e == 0) || (e >= 96 && e <= 158)));
  return __popcll(m) > 8;
}

// ---------------- fused prep kernel (MLP-widened) ----------------
#define B_CVT  338
#define B_XP   1563    // 8 channels/thread
#define B_W1   128
#define B_W2   256
#define B_BND  196
#define B_CNT  831     // 4 edges/thread

struct PrepArgs {
  const void* x;
  const void* src[12];
  const int* ei;
  const int* batch;
};

__global__ __launch_bounds__(256) void prep_k(
    PrepArgs a, float* __restrict__ par, bf16* __restrict__ xb,
    bf16* __restrict__ wt1, bf16* __restrict__ wt2,
    int* __restrict__ gs, int* __restrict__ ge, int* __restrict__ cnt,
    int* __restrict__ rank) {
  int b = blockIdx.x;
  const int tid = threadIdx.x;

  if (b < B_CVT) {                       // ---- param convert -> f32 ----
    const int flag = detect_f32_wave(a.x);
    int idx = b * 256 + tid;
    const void* p; int base;
    if      (idx < P_BL1)  { p = a.src[0];  base = P_WL1; }
    else if (idx < P_WR1)  { p = a.src[1];  base = P_BL1; }
    else if (idx < P_BR1)  { p = a.src[2];  base = P_WR1; }
    else if (idx < P_ATT1) { p = a.src[3];  base = P_BR1; }
    else if (idx < P_BIAS1){ p = a.src[4];  base = P_ATT1; }
    else if (idx < P_WL2)  { p = a.src[5];  base = P_BIAS1; }
    else if (idx < P_BL2)  { p = a.src[6];  base = P_WL2; }
    else if (idx < P_WR2)  { p = a.src[7];  base = P_BL2; }
    else if (idx < P_BR2)  { p = a.src[8];  base = P_WR2; }
    else if (idx < P_ATT2) { p = a.src[9];  base = P_BR2; }
    else if (idx < P_BIAS2){ p = a.src[10]; base = P_ATT2; }
    else                   { p = a.src[11]; base = P_BIAS2; }
    int li = idx - base;
    par[idx] = flag ? ((const float*)p)[li] : (float)((const bf16*)p)[li];
    return;
  }
  b -= B_CVT;
  if (b < B_XP) {                        // ---- x -> xb, 8 ch/thread ----
    const int flag = detect_f32_wave(a.x);
    int gid = b * 256 + tid;
    int n = gid >> 3, k0 = (gid & 7) * 8;
    float v[8];
#pragma unroll
    for (int j = 0; j < 8; j++) {
      int k = k0 + j;
      v[j] = 0.f;
      if (k < IN_F) {
        int idx = n * IN_F + k;
        v[j] = flag ? ((const float*)a.x)[idx] : (float)((const bf16*)a.x)[idx];
      }
    }
    __align__(16) bf16 ob[8];
#pragma unroll
    for (int j = 0; j < 8; j++) ob[j] = (bf16)v[j];
    *(uint4*)(xb + (size_t)n * 64 + k0) = *(uint4*)ob;
    return;
  }
  b -= B_XP;
  if (b < B_W1) {                        // ---- Wt1[n][k] 512x64 ----
    const int flag = detect_f32_wave(a.x);
    int i = b * 256 + tid;
    int n = i >> 6, k = i & 63;
    float v = 0.f;
    if (k < IN_F) {
      const void* W = (n < F1) ? a.src[0] : a.src[2];
      int col = (n < F1) ? n : n - F1;
      int idx = k * F1 + col;
      v = flag ? ((const float*)W)[idx] : (float)((const bf16*)W)[idx];
    }
    wt1[i] = (bf16)v;
    return;
  }
  b -= B_W1;
  if (b < B_W2) {                        // ---- Wt2[n][k] 256x256 ----
    const int flag = detect_f32_wave(a.x);
    int i = b * 256 + tid;
    int n = i >> 8, k = i & 255;
    const void* W = (n < F2) ? a.src[6] : a.src[8];
    int col = (n < F2) ? n : n - F2;
    int idx = k * F2 + col;
    float v = flag ? ((const float*)W)[idx] : (float)((const bf16*)W)[idx];
    wt2[i] = (bf16)v;
    return;
  }
  b -= B_W2;
  if (b < B_BND) {                       // ---- graph bounds (+1 encoding, 0 = unset) ----
    int n = b * 256 + tid;
    if (n >= N_NODES) return;
    int bb = a.batch[n];
    if (n == 0) gs[bb] = 1;
    else {
      int bp = a.batch[n - 1];
      if (bp != bb) { gs[bb] = n + 1; ge[bp] = n; }   // ge = end-exclusive
    }
    if (n == N_NODES - 1) ge[bb] = N_NODES;
    return;
  }
  b -= B_BND;
  {                                      // ---- degree count + rank, 4 edges/thread ----
    int base = b * 1024 + tid;
    int dstv[4]; bool val[4];
#pragma unroll
    for (int i = 0; i < 4; i++) {
      int e = base + i * 256;
      val[i] = e < TOT_E;
      dstv[i] = 0;
      if (val[i])
        dstv[i] = (e < N_EDGES) ? a.ei[N_EDGES + e] : (e - N_EDGES);
    }
#pragma unroll
    for (int i = 0; i < 4; i++) {
      int e = base + i * 256;
      if (val[i]) rank[e] = atomicAdd(&cnt[dstv[i]], 1);
    }
  }
}

// ---------------- fused: GEMM1 (MFMA 32x32x16, LDS-staged epilogue) || scatter ----------------
__global__ __launch_bounds__(256) void gemm1_scatter_k(
    const bf16* __restrict__ xb, const bf16* __restrict__ wt1,
    const float* __restrict__ par,
    fp8_t* __restrict__ xl1, bf16* __restrict__ xr1,
    const int* __restrict__ ei, const int* __restrict__ offs,
    const int* __restrict__ rank, int* __restrict__ csr) {
  __shared__ char lds[24576];            // 8KB fp8 tile + 16KB bf16 tile
  if (blockIdx.x >= GBLK) {              // ---- scatter path (LDS unused) ----
    int base = (blockIdx.x - GBLK) * 1024 + threadIdx.x;
#pragma unroll
    for (int i = 0; i < 4; i++) {
      int e = base + i * 256;
      if (e >= TOT_E) continue;
      int src, dst;
      if (e < N_EDGES) { src = ei[e]; dst = ei[N_EDGES + e]; }
      else             { src = dst = e - N_EDGES; }
      csr[offs[dst] + rank[e]] = src;
    }
    return;
  }
  // ---- gemm1 path ----
  const int w = threadIdx.x >> 6, lane = threadIdx.x & 63;
  const int m0 = blockIdx.x * 32;
  const int colbase = w * 128;
  const int lm = lane & 31;
  const int kh = lane >> 5;

  int arow = m0 + lm; if (arow >= N_NODES) arow = N_NODES - 1;
  short8 afr[4];
#pragma unroll
  for (int kk = 0; kk < 4; kk++)
    afr[kk] = *(const short8*)(xb + (size_t)arow * 64 + kk * 16 + kh * 8);

  f32x16 acc[4] = {};
#pragma unroll
  for (int t = 0; t < 4; t++) {
    int n = colbase + t * 32 + lm;
#pragma unroll
    for (int kk = 0; kk < 4; kk++) {
      short8 b = *(const short8*)(wt1 + (size_t)n * 64 + kk * 16 + kh * 8);
      acc[t] = __builtin_amdgcn_mfma_f32_32x32x16_bf16(afr[kk], b, acc[t], 0, 0, 0);
    }
  }

  // phase 1: C-tile -> LDS (row_local = (reg&3)+8*(reg>>2)+4*kh)
  char* lds8  = lds;                     // [32][256] fp8
  bf16* lds16 = (bf16*)(lds + 8192);     // [32][256] bf16
  if (w < 2) {                           // cols 0..255 -> xl1 (fp8)
#pragma unroll
    for (int t = 0; t < 4; t++) {
      int col = colbase + t * 32 + lm;
      float bv = par[P_BL1 + col];
#pragma unroll
      for (int reg = 0; reg < 16; reg++) {
        int rl = (reg & 3) + 8 * (reg >> 2) + 4 * kh;
        lds8[rl * 256 + col] = f32_to_fp8(acc[t][reg] + bv);
      }
    }
  } else {                               // cols 256..511 -> xr1 (bf16)
#pragma unroll
    for (int t = 0; t < 4; t++) {
      int c = colbase - 256 + t * 32 + lm;
      float bv = par[P_BR1 + c];
#pragma unroll
      for (int reg = 0; reg < 16; reg++) {
        int rl = (reg & 3) + 8 * (reg >> 2) + 4 * kh;
        lds16[rl * 256 + c] = (bf16)(acc[t][reg] + bv);
      }
    }
  }
  __syncthreads();

  // phase 2: coalesced copy-out (16B stores)
  const int tid = threadIdx.x;
#pragma unroll
  for (int i = 0; i < 2; i++) {          // xl1: 32 rows x 256B
    int idx = tid + i * 256;             // 0..511
    int row = idx >> 4, ck = (idx & 15) * 16;
    int grow = m0 + row;
    if (grow < N_NODES)
      *(uint4*)(xl1 + (size_t)grow * F1 + ck) = *(uint4*)(lds8 + row * 256 + ck);
  }
#pragma unroll
  for (int i = 0; i < 4; i++) {          // xr1: 32 rows x 512B
    int idx = tid + i * 256;             // 0..1023
    int row = idx >> 5, ck = (idx & 31) * 16;
    int grow = m0 + row;
    if (grow < N_NODES)
      *(uint4*)((char*)(xr1 + (size_t)grow * F1) + ck) =
          *(uint4*)((char*)(lds16 + row * 256) + ck);
  }
}

// ---------------- GEMM 2 (MFMA 32x32x16, LDS-staged epilogue) ----------------
__global__ __launch_bounds__(256) void gemm2_mfma_k(
    const bf16* __restrict__ h, const bf16* __restrict__ wt2,
    const float* __restrict__ par,
    fp8_t* __restrict__ xl2, bf16* __restrict__ xr2) {
  __shared__ char lds[12288];            // 4KB fp8 + 8KB bf16
  const int w = threadIdx.x >> 6, lane = threadIdx.x & 63;
  const int m0 = blockIdx.x * 32;
  const int colbase = w * 64;
  const int lm = lane & 31;
  const int kh = lane >> 5;

  int arow = m0 + lm; if (arow >= N_NODES) arow = N_NODES - 1;
  const bf16* hrow = h + (size_t)arow * F1 + kh * 8;

  f32x16 acc[2] = {};
#pragma unroll
  for (int kk = 0; kk < 16; kk++) {
    short8 a = *(const short8*)(hrow + kk * 16);
#pragma unroll
    for (int t = 0; t < 2; t++) {
      int n = colbase + t * 32 + lm;
      short8 b = *(const short8*)(wt2 + (size_t)n * 256 + kk * 16 + kh * 8);
      acc[t] = __builtin_amdgcn_mfma_f32_32x32x16_bf16(a, b, acc[t], 0, 0, 0);
    }
  }

  char* lds8  = lds;                     // [32][128] fp8
  bf16* lds16 = (bf16*)(lds + 4096);     // [32][128] bf16
  if (w < 2) {                           // cols 0..127 -> xl2 (fp8)
#pragma unroll
    for (int t = 0; t < 2; t++) {
      int col = colbase + t * 32 + lm;
      float bv = par[P_BL2 + col];
#pragma unroll
      for (int reg = 0; reg < 16; reg++) {
        int rl = (reg & 3) + 8 * (reg >> 2) + 4 * kh;
        lds8[rl * 128 + col] = f32_to_fp8(acc[t][reg] + bv);
      }
    }
  } else {                               // cols 128..255 -> xr2 (bf16)
#pragma unroll
    for (int t = 0; t < 2; t++) {
      int c = colbase - 128 + t * 32 + lm;
      float bv = par[P_BR2 + c];
#pragma unroll
      for (int reg = 0; reg < 16; reg++) {
        int rl = (reg & 3) + 8 * (reg >> 2) + 4 * kh;
        lds16[rl * 128 + c] = (bf16)(acc[t][reg] + bv);
      }
    }
  }
  __syncthreads();

  const int tid = threadIdx.x;
  {                                      // xl2: 32 rows x 128B = 256 x 16B
    int row = tid >> 3, ck = (tid & 7) * 16;
    int grow = m0 + row;
    if (grow < N_NODES)
      *(uint4*)(xl2 + (size_t)grow * F2 + ck) = *(uint4*)(lds8 + row * 128 + ck);
  }
#pragma unroll
  for (int i = 0; i < 2; i++) {          // xr2: 32 rows x 256B = 512 x 16B
    int idx = tid + i * 256;
    int row = idx >> 4, ck = (idx & 15) * 16;
    int grow = m0 + row;
    if (grow < N_NODES)
      *(uint4*)((char*)(xr2 + (size_t)grow * F2) + ck) =
          *(uint4*)((char*)(lds16 + row * 128) + ck);
  }
}

// ---------------- CSR scan (2-phase) ----------------
__global__ __launch_bounds__(1024) void scan_a(const int* __restrict__ cnt,
                                               int* __restrict__ offs,
                                               int* __restrict__ bsum) {
  __shared__ int wsum[16];
  const int t = threadIdx.x;
  const int lane = t & 63, w = t >> 6;
  int idx = blockIdx.x * 1024 + t;
  int v = (idx < N_NODES) ? cnt[idx] : 0;
  int s = v;
#pragma unroll
  for (int off = 1; off < 64; off <<= 1) {
    int u = __shfl_up(s, off, 64);
    if (lane >= off) s += u;
  }
  if (lane == 63) wsum[w] = s;
  __syncthreads();
  int prefix = 0;
  for (int i = 0; i < w; i++) prefix += wsum[i];
  if (idx < N_NODES) offs[idx] = prefix + s - v;
  if (t == 1023) bsum[blockIdx.x] = prefix + s;
}

__global__ void scan_c(const int* __restrict__ bsum, int* __restrict__ offs) {
  const int t = threadIdx.x;
  const int grp = blockIdx.x >> 2;
  __shared__ int sboff;
  if (t < 64) {
    int v = (t < SCAN_BLKS) ? bsum[t] : 0;
    int s = v;
#pragma unroll
    for (int off = 1; off < 64; off <<= 1) {
      int u = __shfl_up(s, off, 64);
      if (t >= off) s += u;
    }
    if (t == grp) sboff = s - v;
  }
  __syncthreads();
  int idx = blockIdx.x * 256 + t;
  if (idx < N_NODES) offs[idx] += sboff;
  if (blockIdx.x == 0 && t == 0) offs[N_NODES] = TOT_E;
}

// ---------------- layer-1 aggregation (R14 shape) ----------------
__global__ __launch_bounds__(256, 4) void agg1_k(
    const fp8_t* __restrict__ xl1, const bf16* __restrict__ xr1,
    const float* __restrict__ par,
    const int* __restrict__ offs, const int* __restrict__ csr,
    bf16* __restrict__ hout) {
  const int dst = blockIdx.x * 4 + (threadIdx.x >> 6);
  if (dst >= N_NODES) return;
  const int lane = threadIdx.x & 63;
  const int g = lane >> 5;        // 2 edge groups
  const int sl = lane & 31;
  const int chb = sl * 8;

  f2 r2[4], a2[4];
  load8bf2(xr1 + (size_t)dst * F1 + chb, r2);
  {
    float4 aa = *(const float4*)(par + P_ATT1 + chb);
    float4 ab = *(const float4*)(par + P_ATT1 + chb + 4);
    a2[0].x = aa.x; a2[0].y = aa.y; a2[1].x = aa.z; a2[1].y = aa.w;
    a2[2].x = ab.x; a2[2].y = ab.y; a2[3].x = ab.z; a2[3].y = ab.w;
  }

  const int e0 = offs[dst], e1 = offs[dst + 1];
  const f2 zf2 = {0.f, 0.f};
  f2 acc2[4];
#pragma unroll
  for (int j = 0; j < 4; j++) acc2[j] = zf2;
  float denom = 0.f;

  const uint2 zq = {0, 0};
  int e = e0 + g;
  bool valid = e < e1;
  uint2 q = valid ? *(const uint2*)(xl1 + (size_t)csr[e] * F1 + chb) : zq;

  for (int base = e0; base < e1; base += 2) {
    const uint2 qc = q;
    const bool vc = valid;
    e += 2;
    valid = e < e1;
    q = valid ? *(const uint2*)(xl1 + (size_t)csr[e] * F1 + chb) : zq;

    f2 v2[4];
    unpack8fp8(qc, v2);
    f2 lt2 = zf2;
#pragma unroll
    for (int j = 0; j < 4; j++)
      lt2 = lrelu2(v2[j] + r2[j]) * a2[j] + lt2;
    float lt = vc ? (lt2.x + lt2.y) : -1e30f;
    lt += __shfl_xor(lt, 1, 64);
    lt += __shfl_xor(lt, 2, 64);
    lt += __shfl_xor(lt, 4, 64);
    float p = __expf(fminf(lt, 60.f));
    denom += p;
    f2 pv; pv.x = p; pv.y = p;
#pragma unroll
    for (int j = 0; j < 4; j++) acc2[j] = pv * v2[j] + acc2[j];
  }

  denom += __shfl_xor(denom, 32, 64);
#pragma unroll
  for (int j = 0; j < 4; j++) {
    acc2[j].x += __shfl_xor(acc2[j].x, 32, 64);
    acc2[j].y += __shfl_xor(acc2[j].y, 32, 64);
  }

  if (g == 0) {
    float inv = 1.f / (denom + EPS_A);
    __align__(16) bf16 ob[8];
#pragma unroll
    for (int j = 0; j < 4; j++) {
      float o0 = fmaxf(acc2[j].x * inv + par[P_BIAS1 + chb + 2*j],     0.f);
      float o1 = fmaxf(acc2[j].y * inv + par[P_BIAS1 + chb + 2*j + 1], 0.f);
      ob[2*j] = (bf16)o0; ob[2*j+1] = (bf16)o1;
    }
    *(uint4*)(hout + (size_t)dst * F1 + chb) = *(uint4*)ob;
  }
}

// ---------------- layer-2 aggregation (R14 shape) ----------------
__global__ __launch_bounds__(256, 4) void agg2_k(
    const fp8_t* __restrict__ xl2, const bf16* __restrict__ xr2,
    const float* __restrict__ par,
    const int* __restrict__ offs, const int* __restrict__ csr,
    bf16* __restrict__ h2) {
  const int dst = blockIdx.x * 4 + (threadIdx.x >> 6);
  if (dst >= N_NODES) return;
  const int lane = threadIdx.x & 63;
  const int g = lane >> 4;        // 4 edge groups
  const int sl = lane & 15;
  const int chb = sl * 8;

  f2 r2[4], a2[4];
  load8bf2(xr2 + (size_t)dst * F2 + chb, r2);
  {
    float4 aa = *(const float4*)(par + P_ATT2 + chb);
    float4 ab = *(const float4*)(par + P_ATT2 + chb + 4);
    a2[0].x = aa.x; a2[0].y = aa.y; a2[1].x = aa.z; a2[1].y = aa.w;
    a2[2].x = ab.x; a2[2].y = ab.y; a2[3].x = ab.z; a2[3].y = ab.w;
  }

  const int e0 = offs[dst], e1 = offs[dst + 1];
  const f2 zf2 = {0.f, 0.f};
  f2 acc2[4];
#pragma unroll
  for (int j = 0; j < 4; j++) acc2[j] = zf2;
  float denom = 0.f;

  const uint2 zq = {0, 0};
  int e = e0 + g;
  bool valid = e < e1;
  uint2 q = valid ? *(const uint2*)(xl2 + (size_t)csr[e] * F2 + chb) : zq;

  for (int base = e0; base < e1; base += 4) {
    const uint2 qc = q;
    const bool vc = valid;
    e += 4;
    valid = e < e1;
    q = valid ? *(const uint2*)(xl2 + (size_t)csr[e] * F2 + chb) : zq;

    f2 v2[4];
    unpack8fp8(qc, v2);
    f2 lt2 = zf2;
#pragma unroll
    for (int j = 0; j < 4; j++)
      lt2 = lrelu2(v2[j] + r2[j]) * a2[j] + lt2;
    float lt = vc ? (lt2.x + lt2.y) : -1e30f;
    lt += __shfl_xor(lt, 1, 64);
    lt += __shfl_xor(lt, 2, 64);
    lt += __shfl_xor(lt, 4, 64);
    lt += __shfl_xor(lt, 8, 64);
    float p = __expf(fminf(lt, 60.f));
    denom += p;
    f2 pv; pv.x = p; pv.y = p;
#pragma unroll
    for (int j = 0; j < 4; j++) acc2[j] = pv * v2[j] + acc2[j];
  }

#pragma unroll
  for (int m = 16; m <= 32; m <<= 1) {
    denom += __shfl_xor(denom, m, 64);
#pragma unroll
    for (int j = 0; j < 4; j++) {
      acc2[j].x += __shfl_xor(acc2[j].x, m, 64);
      acc2[j].y += __shfl_xor(acc2[j].y, m, 64);
    }
  }

  if (g == 0) {
    float inv = 1.f / (denom + EPS_A);
    __align__(16) bf16 ob[8];
#pragma unroll
    for (int j = 0; j < 4; j++) {
      float o0 = fmaxf(acc2[j].x * inv + par[P_BIAS2 + chb + 2*j],     0.f);
      float o1 = fmaxf(acc2[j].y * inv + par[P_BIAS2 + chb + 2*j + 1], 0.f);
      ob[2*j] = (bf16)o0; ob[2*j+1] = (bf16)o1;
    }
    *(uint4*)(h2 + (size_t)dst * F2 + chb) = *(uint4*)ob;
  }
}

// ---------------- pooling: 8 slices/graph + finalize ----------------
__global__ __launch_bounds__(256) void poolp_k(
    const bf16* __restrict__ h2, const int* __restrict__ gs,
    const int* __restrict__ ge, float* __restrict__ psum) {
  const int g = blockIdx.x >> 3, slice = blockIdx.x & 7;
  const int t = threadIdx.x;
  const int c = t & 127, half = t >> 7;
  int s = gs[g] - 1, eex = ge[g];        // +1 encoding; 0 = unset
  if (s < 0 || eex <= s) return;
  float sum = 0.f;
  for (int n = s + slice * 2 + half; n < eex; n += 16)
    sum += (float)h2[(size_t)n * F2 + c];
  atomicAdd(&psum[g * F2 + c], sum);
}

__global__ void poolf_k(const float* __restrict__ psum,
                        const int* __restrict__ gs, const int* __restrict__ ge,
                        const void* __restrict__ x, void* __restrict__ out) {
  int i = blockIdx.x * 256 + threadIdx.x;
  if (i >= NGRAPH * F2) return;
  const int flag = detect_f32_wave(x);
  int g = i >> 7;
  int s = gs[g] - 1, eex = ge[g];
  float cnt = (s >= 0 && eex > s) ? (float)(eex - s) : 1.f;
  float v = psum[i] / cnt;
  if (flag) ((float*)out)[i] = v;
  else      ((bf16*)out)[i] = (bf16)v;
}

// ---------------- launch ----------------
extern "C" void kernel_launch(void* const* d_in, const int* in_sizes, int n_in,
                              void* d_out, int out_size, void* d_ws, size_t ws_size,
                              hipStream_t stream) {
  (void)in_sizes; (void)n_in; (void)out_size; (void)ws_size;
  const void* x     = d_in[0];
  const int*  ei    = (const int*)d_in[1];
  const int*  batch = (const int*)d_in[2];

  char* ws = (char*)d_ws;
  float* par  = (float*)(ws + OFF_PAR);
  fp8_t* xl1 = (fp8_t*)(ws + OFF_XL1);
  bf16* xr1 = (bf16*)(ws + OFF_XR1);
  bf16* h   = (bf16*)(ws + OFF_H);
  fp8_t* xl2 = (fp8_t*)(ws + OFF_XL2);
  bf16* xr2 = (bf16*)(ws + OFF_XR2);
  bf16* h2  = (bf16*)(ws + OFF_H2);
  bf16* xb  = (bf16*)(ws + OFF_XB);
  bf16* wt1 = (bf16*)(ws + OFF_WT1);
  bf16* wt2 = (bf16*)(ws + OFF_WT2);
  int* cnt    = (int*)(ws + OFF_CNT);
  int* offs   = (int*)(ws + OFF_OFFS);
  int* csr    = (int*)(ws + OFF_CSR);
  int* gs     = (int*)(ws + OFF_GS);
  int* ge     = (int*)(ws + OFF_GE);
  int* bsum   = (int*)(ws + OFF_BS);
  float* psum = (float*)(ws + OFF_PSUM);
  int* rank   = (int*)(ws + OFF_RANK);

  // single zero-init: cnt | gs | ge | psum (contiguous)
  hipMemsetAsync(cnt, 0, OFF_ZEND - OFF_CNT, stream);

  PrepArgs pa;
  pa.x = x; pa.ei = ei; pa.batch = batch;
  for (int i = 0; i < 12; i++) pa.src[i] = d_in[3 + i];
  const int prep_blocks = B_CVT + B_XP + B_W1 + B_W2 + B_BND + B_CNT;
  prep_k<<<prep_blocks, 256, 0, stream>>>(pa, par, xb, wt1, wt2, gs, ge, cnt, rank);

  scan_a<<<SCAN_BLKS, 1024, 0, stream>>>(cnt, offs, bsum);
  scan_c<<<(N_NODES + 255) / 256, 256, 0, stream>>>(bsum, offs);

  gemm1_scatter_k<<<GBLK + SBL, 256, 0, stream>>>(xb, wt1, par, xl1, xr1,
                                                  ei, offs, rank, csr);
  agg1_k<<<(N_NODES + 3) / 4, 256, 0, stream>>>(xl1, xr1, par, offs, csr, h);
  gemm2_mfma_k<<<GBLK, 256, 0, stream>>>(h, wt2, par, xl2, xr2);
  agg2_k<<<(N_NODES + 3) / 4, 256, 0, stream>>>(xl2, xr2, par, offs, csr, h2);
  poolp_k<<<NGRAPH * 8, 256, 0, stream>>>(h2, gs, ge, psum);
  poolf_k<<<(NGRAPH * F2 + 255) / 256, 256, 0, stream>>>(psum, gs, ge, x, d_out);
}